// Round 1
// baseline (4846.896 us; speedup 1.0000x reference)
//
#include <hip/hip_runtime.h>
#include <cstdint>
#include <cstddef>

// Problem constants
constexpr int BN   = 8192;   // batch
constexpr int LL   = 8;      // seq len
constexpr int DD   = 128;    // embed dim
constexpr int FVc  = 64;     // vertical filters
constexpr int FHc  = 64;     // horizontal filters
constexpr int FCIN = 8704;   // FV*D + FH*L
constexpr int NBT  = 16;     // batch rows per block

// LDS strides (floats), padded for bank spread
constexpr int XROW = 132;            // row stride: 132 % 32 == 4
constexpr int XBI  = LL * XROW + 8;  // per-sample stride: 1064 % 32 == 8
constexpr int FROW = 132;

// Horizontal conv for one window height H. xb points at this sample's xs base.
// Each of the 16 sub-threads owns 4 filters: f = sub*4 + ff. Produces mx[4] =
// max_j relu(bh + sum_{hp<H,d} x[j+hp][d] * Wh[H-1][f][hp][d]).
template<int H>
__device__ __forceinline__ void hconv_one(const float* __restrict__ xb,
                                          const float4* __restrict__ Wh4,
                                          const float* __restrict__ bh,
                                          int sub, float* __restrict__ mx)
{
    constexpr int NJ = LL - H + 1;
    float s[NJ][4];
    #pragma unroll
    for (int ff = 0; ff < 4; ++ff) {
        float bhv = bh[(H - 1) * FHc + sub * 4 + ff];
        #pragma unroll
        for (int jj = 0; jj < NJ; ++jj) s[jj][ff] = bhv;
    }
    #pragma unroll
    for (int hp = 0; hp < H; ++hp) {
        for (int d4 = 0; d4 < 32; ++d4) {
            float4 w4[4];
            #pragma unroll
            for (int ff = 0; ff < 4; ++ff) {
                size_t widx = (size_t)(((H - 1) * FHc + sub * 4 + ff) * LL + hp) * 32 + d4;
                w4[ff] = Wh4[widx];
            }
            #pragma unroll
            for (int jj = 0; jj < NJ; ++jj) {
                float4 xv = *reinterpret_cast<const float4*>(xb + (jj + hp) * XROW + d4 * 4);
                #pragma unroll
                for (int ff = 0; ff < 4; ++ff) {
                    s[jj][ff] = fmaf(xv.x, w4[ff].x, s[jj][ff]);
                    s[jj][ff] = fmaf(xv.y, w4[ff].y, s[jj][ff]);
                    s[jj][ff] = fmaf(xv.z, w4[ff].z, s[jj][ff]);
                    s[jj][ff] = fmaf(xv.w, w4[ff].w, s[jj][ff]);
                }
            }
        }
    }
    #pragma unroll
    for (int ff = 0; ff < 4; ++ff) {
        float m = 0.f;  // max_j relu(o) == max(0, max_j o)
        #pragma unroll
        for (int jj = 0; jj < NJ; ++jj) m = fmaxf(m, s[jj][ff]);
        mx[ff] = m;
    }
}

__global__ __launch_bounds__(256, 2)
void caser_fused(const int* __restrict__ user_id,
                 const int* __restrict__ seq,
                 const int* __restrict__ item_id,
                 const float* __restrict__ Q,
                 const float* __restrict__ P,
                 const float* __restrict__ Qp,
                 const float* __restrict__ b_item,
                 const float* __restrict__ Wv,
                 const float* __restrict__ bv,
                 const float* __restrict__ Wh,
                 const float* __restrict__ bh,
                 const float* __restrict__ Wfc,
                 const float* __restrict__ bfc,
                 float* __restrict__ out)
{
    __shared__ float xs[NBT * XBI];      // 68096 B
    __shared__ float feat[NBT * FROW];   //  8448 B
    __shared__ float wv_s[FVc * LL];     //  2048 B

    const int t   = threadIdx.x;
    const int bi  = t >> 4;    // sample within tile (0..15)
    const int sub = t & 15;    // worker within sample (0..15)
    const int b0  = blockIdx.x * NBT;
    const int b   = b0 + bi;

    // ---- load Wv into LDS ----
    for (int idx = t; idx < FVc * LL; idx += 256) wv_s[idx] = Wv[idx];

    // ---- gather x = Q[seq] into LDS ----
    const float4* Q4 = reinterpret_cast<const float4*>(Q);
    for (int idx = t; idx < NBT * LL * 32; idx += 256) {
        int c4  = idx & 31;
        int r   = idx >> 5;     // 0..127: sample*8 + row
        int row = r & 7;
        int bb  = r >> 3;
        int it  = seq[(b0 + bb) * LL + row];
        float4 v = Q4[(size_t)it * 32 + c4];
        float* dst = &xs[bb * XBI + row * XROW + c4 * 4];
        dst[0] = v.x; dst[1] = v.y; dst[2] = v.z; dst[3] = v.w;
    }
    __syncthreads();

    float zacc[8];
    #pragma unroll
    for (int i = 0; i < 8; ++i) zacc[i] = 0.f;

    const size_t wrow0 = (size_t)(sub * 8) * FCIN;   // this thread's first Wfc row
    const float* xb = &xs[bi * XBI];
    const float4* Wh4 = reinterpret_cast<const float4*>(Wh);

    // ================= horizontal convs + FC part 2 (cols 8192..8703) ========
    float mx[4];
#define DO_H(H)                                                                 \
    {                                                                           \
        hconv_one<H>(xb, Wh4, bh, sub, mx);                                     \
        __syncthreads();                                                        \
        feat[bi * FROW + sub * 4 + 0] = mx[0];                                  \
        feat[bi * FROW + sub * 4 + 1] = mx[1];                                  \
        feat[bi * FROW + sub * 4 + 2] = mx[2];                                  \
        feat[bi * FROW + sub * 4 + 3] = mx[3];                                  \
        __syncthreads();                                                        \
        const float* wb2 = Wfc + wrow0 + 8192 + (H - 1) * FHc;                  \
        const float* fb  = &feat[bi * FROW];                                    \
        for (int k = 0; k < FHc; k += 4) {                                      \
            float4 fv = *reinterpret_cast<const float4*>(fb + k);               \
            _Pragma("unroll")                                                   \
            for (int ii = 0; ii < 8; ++ii) {                                    \
                const float4 w = *reinterpret_cast<const float4*>(              \
                    wb2 + (size_t)ii * FCIN + k);                               \
                zacc[ii] = fmaf(fv.x, w.x, zacc[ii]);                           \
                zacc[ii] = fmaf(fv.y, w.y, zacc[ii]);                           \
                zacc[ii] = fmaf(fv.z, w.z, zacc[ii]);                           \
                zacc[ii] = fmaf(fv.w, w.w, zacc[ii]);                           \
            }                                                                   \
        }                                                                       \
        __syncthreads();                                                        \
    }
    DO_H(1) DO_H(2) DO_H(3) DO_H(4) DO_H(5) DO_H(6) DO_H(7) DO_H(8)
#undef DO_H

    // ================= vertical conv + FC part 1 (cols 0..8191) ==============
    // Hoist this thread's x slice (all 8 rows, d = sub*8 .. sub*8+7) to regs.
    float xreg[LL][8];
    #pragma unroll
    for (int l = 0; l < LL; ++l) {
        const float* src = &xs[bi * XBI + l * XROW + sub * 8];
        #pragma unroll
        for (int j = 0; j < 8; ++j) xreg[l][j] = src[j];
    }

    for (int f = 0; f < FVc; ++f) {
        float wl[LL];
        #pragma unroll
        for (int l = 0; l < LL; ++l) wl[l] = wv_s[f * LL + l];
        float bvf = bv[f];
        #pragma unroll
        for (int j = 0; j < 8; ++j) {
            float s = bvf;
            #pragma unroll
            for (int l = 0; l < LL; ++l) s = fmaf(xreg[l][j], wl[l], s);
            feat[bi * FROW + sub * 8 + j] = fmaxf(s, 0.f);
        }
        __syncthreads();
        const float* wb = Wfc + wrow0 + f * DD;
        const float* fb = &feat[bi * FROW];
        for (int k = 0; k < DD; k += 4) {
            float4 fv = *reinterpret_cast<const float4*>(fb + k);
            #pragma unroll
            for (int ii = 0; ii < 8; ++ii) {
                const float4 w = *reinterpret_cast<const float4*>(
                    wb + (size_t)ii * FCIN + k);
                zacc[ii] = fmaf(fv.x, w.x, zacc[ii]);
                zacc[ii] = fmaf(fv.y, w.y, zacc[ii]);
                zacc[ii] = fmaf(fv.z, w.z, zacc[ii]);
                zacc[ii] = fmaf(fv.w, w.w, zacc[ii]);
            }
        }
        __syncthreads();
    }

    // ================= epilogue ==============================================
    const int i0 = sub * 8;
    float zt[8];
    #pragma unroll
    for (int ii = 0; ii < 8; ++ii) zt[ii] = fmaxf(zacc[ii] + bfc[i0 + ii], 0.f);

    const int item = item_id[b];
    const int user = user_id[b];
    const float* qp = Qp + (size_t)item * (2 * DD);
    const float* pu = P + (size_t)user * DD;
    float part = 0.f;
    #pragma unroll
    for (int ii = 0; ii < 8; ++ii) part = fmaf(zt[ii], qp[i0 + ii], part);
    #pragma unroll
    for (int ii = 0; ii < 8; ++ii) part = fmaf(pu[i0 + ii], qp[DD + i0 + ii], part);
    #pragma unroll
    for (int off = 1; off < 16; off <<= 1) part += __shfl_xor(part, off, 64);
    if (sub == 0) out[b] = part + b_item[item];
}

extern "C" void kernel_launch(void* const* d_in, const int* in_sizes, int n_in,
                              void* d_out, int out_size, void* d_ws, size_t ws_size,
                              hipStream_t stream)
{
    const int*   user_id = (const int*)  d_in[0];
    const int*   seq     = (const int*)  d_in[1];
    const int*   item_id = (const int*)  d_in[2];
    const float* Q       = (const float*)d_in[3];
    const float* P       = (const float*)d_in[4];
    const float* Qp      = (const float*)d_in[5];
    const float* b_item  = (const float*)d_in[6];
    const float* Wv      = (const float*)d_in[7];
    const float* bv      = (const float*)d_in[8];
    const float* Wh      = (const float*)d_in[9];
    const float* bh      = (const float*)d_in[10];
    const float* Wfc     = (const float*)d_in[11];
    const float* bfc     = (const float*)d_in[12];
    float* out = (float*)d_out;

    dim3 grid(BN / NBT), block(256);
    hipLaunchKernelGGL(caser_fused, grid, block, 0, stream,
                       user_id, seq, item_id, Q, P, Qp, b_item,
                       Wv, bv, Wh, bh, Wfc, bfc, out);
}

// Round 6
// 4601.814 us; speedup vs baseline: 1.0533x; 1.0533x over previous
//
#include <hip/hip_runtime.h>
#include <cstdint>
#include <cstddef>

typedef short bf16x8 __attribute__((ext_vector_type(8)));
typedef float f32x4  __attribute__((ext_vector_type(4)));

#define MFMA16(A, B, C) __builtin_amdgcn_mfma_f32_16x16x32_bf16(A, B, C, 0, 0, 0)

constexpr int XSTR = 1032;   // u16 row stride per sample strip (2064 B, 16B-aligned)
constexpr int WSTR = 136;    // u16 stride for staged Wh filter rows (272 B, 16B-aligned)

__device__ __forceinline__ unsigned short f2bf(float x) {
    unsigned u = __float_as_uint(x);
    unsigned r = u + 0x7fffu + ((u >> 16) & 1u);
    return (unsigned short)(r >> 16);
}
__device__ __forceinline__ float bf2f(unsigned short h) {
    return __uint_as_float(((unsigned)h) << 16);
}
__device__ __forceinline__ bf16x8 load8_f32(const float* __restrict__ s) {
    float4 a = *(const float4*)s;
    float4 b = *(const float4*)(s + 4);
    bf16x8 r;
    r[0]=(short)f2bf(a.x); r[1]=(short)f2bf(a.y); r[2]=(short)f2bf(a.z); r[3]=(short)f2bf(a.w);
    r[4]=(short)f2bf(b.x); r[5]=(short)f2bf(b.y); r[6]=(short)f2bf(b.z); r[7]=(short)f2bf(b.w);
    return r;
}

// FC B-frag (16x16x32): lane element j = Wfc[ntile*16+(lane&15)][kg*32+(lane>>4)*8+j]
__device__ __forceinline__ bf16x8 fc_bfrag(const float* __restrict__ Wfc,
                                           int kg, int ntile, int lane)
{
    const float* s = Wfc + (size_t)(ntile * 16 + (lane & 15)) * 8704
                         + kg * 32 + (lane >> 4) * 8;
    return load8_f32(s);
}

// ============ VALU hconv accumulate: windows [J0, J0+CNT), one hp ============
template<int NJ, int J0, int CNT>
__device__ __forceinline__ void hwin_acc(const unsigned short* __restrict__ xs,
                                         const unsigned short* __restrict__ wst,
                                         int s, int sub, int hp, float (&acc)[NJ][4])
{
    #pragma unroll
    for (int d8 = 0; d8 < 16; ++d8) {
        float xvf[CNT][8];
        #pragma unroll
        for (int j = 0; j < CNT; ++j) {
            bf16x8 xv = *(const bf16x8*)(xs + s * XSTR + (J0 + j + hp) * 128 + d8 * 8);
            #pragma unroll
            for (int e = 0; e < 8; ++e) xvf[j][e] = bf2f((unsigned short)xv[e]);
        }
        #pragma unroll
        for (int ff = 0; ff < 4; ++ff) {
            bf16x8 wv = *(const bf16x8*)(wst + (sub * 4 + ff) * WSTR + d8 * 8);
            #pragma unroll
            for (int e = 0; e < 8; ++e) {
                const float wf = bf2f((unsigned short)wv[e]);
                #pragma unroll
                for (int j = 0; j < CNT; ++j)
                    acc[J0 + j][ff] = fmaf(xvf[j][e], wf, acc[J0 + j][ff]);
            }
        }
    }
}

// ===== one h-step: VALU hconv (R1-proven math) -> feat chunk -> FC MFMA ======
template<int H>
__device__ __forceinline__ void hstep_valu(
    const unsigned short* __restrict__ xs, unsigned short* __restrict__ feat,
    unsigned short* __restrict__ wst,
    const float* __restrict__ Wh, const float* __restrict__ bh,
    const float* __restrict__ Wfc,
    int t, int lane, int laneA, int w, f32x4 (&FCC)[2][2])
{
    constexpr int NJ = 9 - H;
    const int s = t >> 4, sub = t & 15;

    float acc[NJ][4];
    #pragma unroll
    for (int ff = 0; ff < 4; ++ff) {
        const float bhv = bh[(H - 1) * 64 + sub * 4 + ff];
        #pragma unroll
        for (int j = 0; j < NJ; ++j) acc[j][ff] = bhv;
    }

    #pragma unroll 1
    for (int hp = 0; hp < H; ++hp) {
        __syncthreads();   // protect wst (and, at hp==0, feat/wst from prev step)
        {   // stage Wh[H-1][:, hp, :] (64x128) -> wst bf16 [64][WSTR]
            const int f = t >> 3, dg = t & 7;
            const float* src = Wh + (((size_t)(H - 1) * 64 + f) * 8 + hp) * 128 + dg * 16;
            unsigned short tmp[16];
            #pragma unroll
            for (int i = 0; i < 16; ++i) tmp[i] = f2bf(src[i]);
            *(uint4*)(wst + f * WSTR + dg * 16)     = *(const uint4*)&tmp[0];
            *(uint4*)(wst + f * WSTR + dg * 16 + 8) = *(const uint4*)&tmp[8];
        }
        __syncthreads();
        constexpr int NJA = (NJ + 1) / 2;
        hwin_acc<NJ, 0, NJA>(xs, wst, s, sub, hp, acc);
        if constexpr (NJ - NJA > 0)
            hwin_acc<NJ, NJA, NJ - NJA>(xs, wst, s, sub, hp, acc);
    }

    // relu + max over windows, write 4 bf16 into feat chunk [32][64]
    float mx[4];
    #pragma unroll
    for (int ff = 0; ff < 4; ++ff) {
        float m = 0.f;
        #pragma unroll
        for (int j = 0; j < NJ; ++j) m = fmaxf(m, acc[j][ff]);
        mx[ff] = m;
    }
    {
        uint2 pk;
        pk.x = (unsigned)f2bf(mx[0]) | ((unsigned)f2bf(mx[1]) << 16);
        pk.y = (unsigned)f2bf(mx[2]) | ((unsigned)f2bf(mx[3]) << 16);
        *(uint2*)(feat + s * XSTR + sub * 4) = pk;
    }
    __syncthreads();
    {   // FC on this 64-wide K chunk: kg = 256 + (H-1)*2 + kh
        const int kh = w & 1, ng = w >> 1;
        const int kg = 256 + (H - 1) * 2 + kh;
        bf16x8 B0 = fc_bfrag(Wfc, kg, ng * 2,     lane);
        bf16x8 B1 = fc_bfrag(Wfc, kg, ng * 2 + 1, lane);
        bf16x8 A0 = *(const bf16x8*)(feat + laneA + kh * 32);
        bf16x8 A1 = *(const bf16x8*)(feat + 16 * XSTR + laneA + kh * 32);
        FCC[0][0] = MFMA16(A0, B0, FCC[0][0]);
        FCC[0][1] = MFMA16(A0, B1, FCC[0][1]);
        FCC[1][0] = MFMA16(A1, B0, FCC[1][0]);
        FCC[1][1] = MFMA16(A1, B1, FCC[1][1]);
    }
}

// ============================ main fused kernel ==============================
__global__ __launch_bounds__(512, 1)
void caser_main(const int* __restrict__ user_id,
                const int* __restrict__ seq,
                const int* __restrict__ item_id,
                const float* __restrict__ Q,
                const float* __restrict__ Pmat,
                const float* __restrict__ Qp,
                const float* __restrict__ b_item,
                const float* __restrict__ Wv,
                const float* __restrict__ bv,
                const float* __restrict__ Wh,
                const float* __restrict__ bh,
                const float* __restrict__ Wfc,
                const float* __restrict__ bfc,
                float* __restrict__ out)
{
    __shared__ unsigned short xs[32 * XSTR];     // 66048 B  x = Q[seq], bf16
    __shared__ unsigned short feat[32 * XSTR];   // 66048 B  FC A-operand chunks
    __shared__ float cand[2 * 32 * 68];          // 17408 B  wstage / zbuf
    __shared__ float wv_s[576];                  //  2304 B  Wv + bv

    const int t = threadIdx.x;
    const int lane = t & 63;
    const int w = t >> 6;
    const int b0 = blockIdx.x * 32;
    const int laneA = (lane & 15) * XSTR + (lane >> 4) * 8;

    // ---------------- phase 0: weights + x gather ----------------
    // BUGFIX (R2-R5): 512-thread block must cover all 576 entries — the old
    // `if (t < 576)` guard left wv_s[512..575] (= bv) UNINITIALIZED.
    for (int idx = t; idx < 576; idx += 512)
        wv_s[idx] = (idx < 512) ? Wv[idx] : bv[idx - 512];
    {
        const int r = t >> 1, half = t & 1;
        const int s = r >> 3, l = r & 7;
        const int it = seq[(b0 + s) * 8 + l];
        const float4* src = (const float4*)(Q + (size_t)it * 128 + half * 64);
        unsigned short* dst = xs + s * XSTR + l * 128 + half * 64;
        #pragma unroll
        for (int i = 0; i < 16; ++i) {
            float4 v = src[i];
            uint2 pk;
            pk.x = (unsigned)f2bf(v.x) | ((unsigned)f2bf(v.y) << 16);
            pk.y = (unsigned)f2bf(v.z) | ((unsigned)f2bf(v.w) << 16);
            *(uint2*)(dst + i * 4) = pk;
        }
    }
    __syncthreads();

    // vconv x slice -> regs: thread (sv=t&31, dq=t>>5) owns d = dq*8..+7
    const int sv = t & 31, dq = t >> 5;
    float xr[8][8];
    #pragma unroll
    for (int l = 0; l < 8; ++l) {
        bf16x8 v = *(const bf16x8*)(xs + sv * XSTR + l * 128 + dq * 8);
        #pragma unroll
        for (int i = 0; i < 8; ++i) xr[l][i] = bf2f((unsigned short)v[i]);
    }

    f32x4 FCC[2][2] = {};
    const int kh = w & 1, ng = w >> 1;

    // ---------------- phase 1: vconv + FC (k = 0..8191) ----------------
    for (int c = 0; c < 8; ++c) {
        #pragma unroll
        for (int fl = 0; fl < 8; ++fl) {
            const int f = c * 8 + fl;
            const float bvv = wv_s[512 + f];
            float acc[8];
            #pragma unroll
            for (int i = 0; i < 8; ++i) acc[i] = bvv;
            #pragma unroll
            for (int l = 0; l < 8; ++l) {
                const float wl = wv_s[f * 8 + l];
                #pragma unroll
                for (int i = 0; i < 8; ++i) acc[i] = fmaf(xr[l][i], wl, acc[i]);
            }
            uint4 pk;
            pk.x = (unsigned)f2bf(fmaxf(acc[0], 0.f)) | ((unsigned)f2bf(fmaxf(acc[1], 0.f)) << 16);
            pk.y = (unsigned)f2bf(fmaxf(acc[2], 0.f)) | ((unsigned)f2bf(fmaxf(acc[3], 0.f)) << 16);
            pk.z = (unsigned)f2bf(fmaxf(acc[4], 0.f)) | ((unsigned)f2bf(fmaxf(acc[5], 0.f)) << 16);
            pk.w = (unsigned)f2bf(fmaxf(acc[6], 0.f)) | ((unsigned)f2bf(fmaxf(acc[7], 0.f)) << 16);
            *(uint4*)(feat + sv * XSTR + fl * 128 + dq * 8) = pk;
        }
        __syncthreads();
        #pragma unroll
        for (int ks = 0; ks < 16; ++ks) {
            const int kl = kh * 16 + ks;
            const int kg = c * 32 + kl;
            bf16x8 B0 = fc_bfrag(Wfc, kg, ng * 2,     lane);
            bf16x8 B1 = fc_bfrag(Wfc, kg, ng * 2 + 1, lane);
            bf16x8 A0 = *(const bf16x8*)(feat + laneA + kl * 32);
            bf16x8 A1 = *(const bf16x8*)(feat + 16 * XSTR + laneA + kl * 32);
            FCC[0][0] = MFMA16(A0, B0, FCC[0][0]);
            FCC[0][1] = MFMA16(A0, B1, FCC[0][1]);
            FCC[1][0] = MFMA16(A1, B0, FCC[1][0]);
            FCC[1][1] = MFMA16(A1, B1, FCC[1][1]);
        }
        __syncthreads();
    }

    // ---------------- phase 2: VALU hconv h=1..8 + FC (k = 8192..8703) ----
    unsigned short* wst = (unsigned short*)cand;
    hstep_valu<1>(xs, feat, wst, Wh, bh, Wfc, t, lane, laneA, w, FCC);
    hstep_valu<2>(xs, feat, wst, Wh, bh, Wfc, t, lane, laneA, w, FCC);
    hstep_valu<3>(xs, feat, wst, Wh, bh, Wfc, t, lane, laneA, w, FCC);
    hstep_valu<4>(xs, feat, wst, Wh, bh, Wfc, t, lane, laneA, w, FCC);
    hstep_valu<5>(xs, feat, wst, Wh, bh, Wfc, t, lane, laneA, w, FCC);
    hstep_valu<6>(xs, feat, wst, Wh, bh, Wfc, t, lane, laneA, w, FCC);
    hstep_valu<7>(xs, feat, wst, Wh, bh, Wfc, t, lane, laneA, w, FCC);
    hstep_valu<8>(xs, feat, wst, Wh, bh, Wfc, t, lane, laneA, w, FCC);

    // ---------------- epilogue: merge K-halves, relu, score --------------
    float* zbuf = cand;   // [32][132]
    if (kh == 1) {
        #pragma unroll
        for (int m = 0; m < 2; ++m)
            #pragma unroll
            for (int nt = 0; nt < 2; ++nt)
                #pragma unroll
                for (int r = 0; r < 4; ++r)
                    zbuf[(m * 16 + (lane >> 4) * 4 + r) * 132 +
                         ng * 32 + nt * 16 + (lane & 15)] = FCC[m][nt][r];
    }
    __syncthreads();
    if (kh == 0) {
        #pragma unroll
        for (int m = 0; m < 2; ++m)
            #pragma unroll
            for (int nt = 0; nt < 2; ++nt) {
                const int o = ng * 32 + nt * 16 + (lane & 15);
                const float bfcv = bfc[o];
                #pragma unroll
                for (int r = 0; r < 4; ++r) {
                    const int idx = (m * 16 + (lane >> 4) * 4 + r) * 132 + o;
                    zbuf[idx] = fmaxf(zbuf[idx] + FCC[m][nt][r] + bfcv, 0.f);
                }
            }
    }
    __syncthreads();
    {
        const int s = t >> 4, l16 = t & 15, o0 = l16 * 8;
        const int b = b0 + s;
        const int item = item_id[b];
        const int user = user_id[b];
        const float* qp = Qp + (size_t)item * 256;
        const float* pu = Pmat + (size_t)user * 128;
        float acc2 = 0.f;
        #pragma unroll
        for (int i = 0; i < 8; ++i) acc2 = fmaf(zbuf[s * 132 + o0 + i], qp[o0 + i], acc2);
        #pragma unroll
        for (int i = 0; i < 8; ++i) acc2 = fmaf(pu[o0 + i], qp[128 + o0 + i], acc2);
        acc2 += __shfl_xor(acc2, 1, 16);
        acc2 += __shfl_xor(acc2, 2, 16);
        acc2 += __shfl_xor(acc2, 4, 16);
        acc2 += __shfl_xor(acc2, 8, 16);
        if (l16 == 0) out[b] = acc2 + b_item[item];
    }
}

extern "C" void kernel_launch(void* const* d_in, const int* in_sizes, int n_in,
                              void* d_out, int out_size, void* d_ws, size_t ws_size,
                              hipStream_t stream)
{
    const int*   user_id = (const int*)  d_in[0];
    const int*   seq     = (const int*)  d_in[1];
    const int*   item_id = (const int*)  d_in[2];
    const float* Q       = (const float*)d_in[3];
    const float* Pmat    = (const float*)d_in[4];
    const float* Qp      = (const float*)d_in[5];
    const float* b_item  = (const float*)d_in[6];
    const float* Wv      = (const float*)d_in[7];
    const float* bv      = (const float*)d_in[8];
    const float* Wh      = (const float*)d_in[9];
    const float* bh      = (const float*)d_in[10];
    const float* Wfc     = (const float*)d_in[11];
    const float* bfc     = (const float*)d_in[12];
    float* out = (float*)d_out;

    hipLaunchKernelGGL(caser_main, dim3(256), dim3(512), 0, stream,
                       user_id, seq, item_id, Q, Pmat, Qp, b_item,
                       Wv, bv, Wh, bh, Wfc, bfc, out);
}

// Round 7
// 303.904 us; speedup vs baseline: 15.9487x; 15.1423x over previous
//
#include <hip/hip_runtime.h>
#include <cstdint>
#include <cstddef>

typedef short bf16x8 __attribute__((ext_vector_type(8)));
typedef float f32x4  __attribute__((ext_vector_type(4)));

#define MFMA16(A, B, C) __builtin_amdgcn_mfma_f32_16x16x32_bf16(A, B, C, 0, 0, 0)

constexpr int XSTR = 1032;   // u16 row stride per sample strip (2064 B, 16B-aligned)

__device__ __forceinline__ unsigned short f2bf(float x) {
    unsigned u = __float_as_uint(x);
    unsigned r = u + 0x7fffu + ((u >> 16) & 1u);
    return (unsigned short)(r >> 16);
}
__device__ __forceinline__ float bf2f(unsigned short h) {
    return __uint_as_float(((unsigned)h) << 16);
}
__device__ __forceinline__ bf16x8 load8_f32(const float* __restrict__ s) {
    float4 a = *(const float4*)s;
    float4 b = *(const float4*)(s + 4);
    bf16x8 r;
    r[0]=(short)f2bf(a.x); r[1]=(short)f2bf(a.y); r[2]=(short)f2bf(a.z); r[3]=(short)f2bf(a.w);
    r[4]=(short)f2bf(b.x); r[5]=(short)f2bf(b.y); r[6]=(short)f2bf(b.z); r[7]=(short)f2bf(b.w);
    return r;
}

// FC B-frag (16x16x32): lane element j = Wfc[ntile*16+(lane&15)][kg*32+(lane>>4)*8+j]
// (validated by R6 pass)
__device__ __forceinline__ bf16x8 fc_bfrag(const float* __restrict__ Wfc,
                                           int kg, int ntile, int lane)
{
    const float* s = Wfc + (size_t)(ntile * 16 + (lane & 15)) * 8704
                         + kg * 32 + (lane >> 4) * 8;
    return load8_f32(s);
}
// hconv B-frag: k = kstep*32+(lane>>4)*8+j -> Wh[H-1][ntile*16+(lane&15)][k>>7][k&127]
__device__ __forceinline__ bf16x8 wh_bfrag(const float* __restrict__ Wh,
                                           int H, int kstep, int ntile, int lane)
{
    const int k = kstep * 32 + (lane >> 4) * 8;
    const float* s = Wh + ((((size_t)(H - 1) * 64 + ntile * 16 + (lane & 15)) * 8
                           + (k >> 7)) * 128 + (k & 127));
    return load8_f32(s);
}

// ===================== hconv MFMA (one h, one j-parity) ======================
// D[sample=(lane>>4)*4+r][filter_local=lane&15]  (m89 layout, R6-validated)
template<int H, int PP>
__device__ __forceinline__ void hconv_compute(
    const unsigned short* __restrict__ xs,
    const float* __restrict__ Wh, const float* __restrict__ bh,
    int m, int n2, int lane, int laneA, float mx[2][4])
{
    constexpr int NJ = 9 - H;
    constexpr int NJS = (PP == 0) ? ((NJ + 1) / 2) : (NJ / 2);
    if constexpr (NJS > 0) {
        f32x4 C[NJS][2] = {};
        const unsigned short* xbase = xs + m * 16 * XSTR + laneA;
        #pragma unroll
        for (int kstep = 0; kstep < 4 * H; ++kstep) {
            const int hp = kstep >> 2, d0 = (kstep & 3) * 32;
            bf16x8 B0 = wh_bfrag(Wh, H, kstep, n2 * 2,     lane);
            bf16x8 B1 = wh_bfrag(Wh, H, kstep, n2 * 2 + 1, lane);
            #pragma unroll
            for (int idx = 0; idx < NJS; ++idx) {
                const int j = PP + 2 * idx;
                bf16x8 A = *(const bf16x8*)(xbase + (j + hp) * 128 + d0);
                C[idx][0] = MFMA16(A, B0, C[idx][0]);
                C[idx][1] = MFMA16(A, B1, C[idx][1]);
            }
        }
        #pragma unroll
        for (int nt = 0; nt < 2; ++nt) {
            const float bhv = bh[(H - 1) * 64 + n2 * 32 + nt * 16 + (lane & 15)];
            #pragma unroll
            for (int idx = 0; idx < NJS; ++idx)
                #pragma unroll
                for (int r = 0; r < 4; ++r)
                    mx[nt][r] = fmaxf(mx[nt][r], fmaxf(C[idx][nt][r] + bhv, 0.f));
        }
    }
}

// one full h-step: hconv MFMA -> parity merge -> feat chunk -> FC accumulate
template<int H>
__device__ __forceinline__ void hstep(
    const unsigned short* __restrict__ xs, unsigned short* __restrict__ feat,
    float* __restrict__ cand,
    const float* __restrict__ Wh, const float* __restrict__ Wfc,
    const float* __restrict__ bh,
    int t, int lane, int laneA, int w, f32x4 (&FCC)[2][2])
{
    const int hm = w & 1, hn2 = (w >> 1) & 1, pj = w >> 2;
    const int kh = w & 1, ng = w >> 1;
    float mx[2][4] = {};
    if (pj == 0) hconv_compute<H, 0>(xs, Wh, bh, hm, hn2, lane, laneA, mx);
    else         hconv_compute<H, 1>(xs, Wh, bh, hm, hn2, lane, laneA, mx);
    #pragma unroll
    for (int nt = 0; nt < 2; ++nt)
        #pragma unroll
        for (int r = 0; r < 4; ++r)
            cand[pj * 2176 + (hm * 16 + (lane >> 4) * 4 + r) * 68 +
                 hn2 * 32 + nt * 16 + (lane & 15)] = mx[nt][r];
    __syncthreads();
    {   // merge 2 parity candidates -> bf16 feat chunk [32][64]
        const int s = t >> 4, f0 = (t & 15) * 4;
        float4 a = *(const float4*)&cand[s * 68 + f0];
        float4 b = *(const float4*)&cand[2176 + s * 68 + f0];
        uint2 pk;
        pk.x = (unsigned)f2bf(fmaxf(a.x, b.x)) | ((unsigned)f2bf(fmaxf(a.y, b.y)) << 16);
        pk.y = (unsigned)f2bf(fmaxf(a.z, b.z)) | ((unsigned)f2bf(fmaxf(a.w, b.w)) << 16);
        *(uint2*)(feat + s * XSTR + f0) = pk;
    }
    __syncthreads();
    {   // FC on this 64-wide K chunk: kg = 256 + (H-1)*2 + kh
        const int kg = 256 + (H - 1) * 2 + kh;
        bf16x8 B0 = fc_bfrag(Wfc, kg, ng * 2,     lane);
        bf16x8 B1 = fc_bfrag(Wfc, kg, ng * 2 + 1, lane);
        bf16x8 A0 = *(const bf16x8*)(feat + laneA + kh * 32);
        bf16x8 A1 = *(const bf16x8*)(feat + 16 * XSTR + laneA + kh * 32);
        FCC[0][0] = MFMA16(A0, B0, FCC[0][0]);
        FCC[0][1] = MFMA16(A0, B1, FCC[0][1]);
        FCC[1][0] = MFMA16(A1, B0, FCC[1][0]);
        FCC[1][1] = MFMA16(A1, B1, FCC[1][1]);
    }
    __syncthreads();   // protect cand for next step / zbuf reuse
}

// ============================ main fused kernel ==============================
__global__ __launch_bounds__(512, 1)
void caser_main(const int* __restrict__ user_id,
                const int* __restrict__ seq,
                const int* __restrict__ item_id,
                const float* __restrict__ Q,
                const float* __restrict__ Pmat,
                const float* __restrict__ Qp,
                const float* __restrict__ b_item,
                const float* __restrict__ Wv,
                const float* __restrict__ bv,
                const float* __restrict__ Wh,
                const float* __restrict__ bh,
                const float* __restrict__ Wfc,
                const float* __restrict__ bfc,
                float* __restrict__ out)
{
    __shared__ unsigned short xs[32 * XSTR];     // 66048 B  x = Q[seq], bf16
    __shared__ unsigned short feat[32 * XSTR];   // 66048 B  FC A-operand chunks
    __shared__ float cand[2 * 32 * 68];          // 17408 B  hconv cands / zbuf
    __shared__ float wv_s[576];                  //  2304 B  Wv + bv

    const int t = threadIdx.x;
    const int lane = t & 63;
    const int w = t >> 6;
    const int b0 = blockIdx.x * 32;
    const int laneA = (lane & 15) * XSTR + (lane >> 4) * 8;

    // ---------------- phase 0: weights + x gather ----------------
    // (R6 bugfix retained: strided loop covers all 576 entries)
    for (int idx = t; idx < 576; idx += 512)
        wv_s[idx] = (idx < 512) ? Wv[idx] : bv[idx - 512];
    {
        const int r = t >> 1, half = t & 1;
        const int s = r >> 3, l = r & 7;
        const int it = seq[(b0 + s) * 8 + l];
        const float4* src = (const float4*)(Q + (size_t)it * 128 + half * 64);
        unsigned short* dst = xs + s * XSTR + l * 128 + half * 64;
        #pragma unroll
        for (int i = 0; i < 16; ++i) {
            float4 v = src[i];
            uint2 pk;
            pk.x = (unsigned)f2bf(v.x) | ((unsigned)f2bf(v.y) << 16);
            pk.y = (unsigned)f2bf(v.z) | ((unsigned)f2bf(v.w) << 16);
            *(uint2*)(dst + i * 4) = pk;
        }
    }
    __syncthreads();

    // vconv x slice -> regs: thread (sv=t&31, dq=t>>5) owns d = dq*8..+7
    const int sv = t & 31, dq = t >> 5;
    float xr[8][8];
    #pragma unroll
    for (int l = 0; l < 8; ++l) {
        bf16x8 v = *(const bf16x8*)(xs + sv * XSTR + l * 128 + dq * 8);
        #pragma unroll
        for (int i = 0; i < 8; ++i) xr[l][i] = bf2f((unsigned short)v[i]);
    }

    f32x4 FCC[2][2] = {};
    const int kh = w & 1, ng = w >> 1;

    // ---------------- phase 1: vconv + FC (k = 0..8191) ----------------
    for (int c = 0; c < 8; ++c) {
        #pragma unroll
        for (int fl = 0; fl < 8; ++fl) {
            const int f = c * 8 + fl;
            const float bvv = wv_s[512 + f];
            float acc[8];
            #pragma unroll
            for (int i = 0; i < 8; ++i) acc[i] = bvv;
            #pragma unroll
            for (int l = 0; l < 8; ++l) {
                const float wl = wv_s[f * 8 + l];
                #pragma unroll
                for (int i = 0; i < 8; ++i) acc[i] = fmaf(xr[l][i], wl, acc[i]);
            }
            uint4 pk;
            pk.x = (unsigned)f2bf(fmaxf(acc[0], 0.f)) | ((unsigned)f2bf(fmaxf(acc[1], 0.f)) << 16);
            pk.y = (unsigned)f2bf(fmaxf(acc[2], 0.f)) | ((unsigned)f2bf(fmaxf(acc[3], 0.f)) << 16);
            pk.z = (unsigned)f2bf(fmaxf(acc[4], 0.f)) | ((unsigned)f2bf(fmaxf(acc[5], 0.f)) << 16);
            pk.w = (unsigned)f2bf(fmaxf(acc[6], 0.f)) | ((unsigned)f2bf(fmaxf(acc[7], 0.f)) << 16);
            *(uint4*)(feat + sv * XSTR + fl * 128 + dq * 8) = pk;
        }
        __syncthreads();
        #pragma unroll
        for (int ks = 0; ks < 16; ++ks) {
            const int kl = kh * 16 + ks;
            const int kg = c * 32 + kl;
            bf16x8 B0 = fc_bfrag(Wfc, kg, ng * 2,     lane);
            bf16x8 B1 = fc_bfrag(Wfc, kg, ng * 2 + 1, lane);
            bf16x8 A0 = *(const bf16x8*)(feat + laneA + kl * 32);
            bf16x8 A1 = *(const bf16x8*)(feat + 16 * XSTR + laneA + kl * 32);
            FCC[0][0] = MFMA16(A0, B0, FCC[0][0]);
            FCC[0][1] = MFMA16(A0, B1, FCC[0][1]);
            FCC[1][0] = MFMA16(A1, B0, FCC[1][0]);
            FCC[1][1] = MFMA16(A1, B1, FCC[1][1]);
        }
        __syncthreads();
    }

    // ---------------- phase 2: MFMA hconv h=1..8 + FC (k = 8192..8703) ----
    hstep<1>(xs, feat, cand, Wh, Wfc, bh, t, lane, laneA, w, FCC);
    hstep<2>(xs, feat, cand, Wh, Wfc, bh, t, lane, laneA, w, FCC);
    hstep<3>(xs, feat, cand, Wh, Wfc, bh, t, lane, laneA, w, FCC);
    hstep<4>(xs, feat, cand, Wh, Wfc, bh, t, lane, laneA, w, FCC);
    hstep<5>(xs, feat, cand, Wh, Wfc, bh, t, lane, laneA, w, FCC);
    hstep<6>(xs, feat, cand, Wh, Wfc, bh, t, lane, laneA, w, FCC);
    hstep<7>(xs, feat, cand, Wh, Wfc, bh, t, lane, laneA, w, FCC);
    hstep<8>(xs, feat, cand, Wh, Wfc, bh, t, lane, laneA, w, FCC);

    // ---------------- epilogue: merge K-halves, relu, score --------------
    float* zbuf = cand;   // [32][132]
    if (kh == 1) {
        #pragma unroll
        for (int m = 0; m < 2; ++m)
            #pragma unroll
            for (int nt = 0; nt < 2; ++nt)
                #pragma unroll
                for (int r = 0; r < 4; ++r)
                    zbuf[(m * 16 + (lane >> 4) * 4 + r) * 132 +
                         ng * 32 + nt * 16 + (lane & 15)] = FCC[m][nt][r];
    }
    __syncthreads();
    if (kh == 0) {
        #pragma unroll
        for (int m = 0; m < 2; ++m)
            #pragma unroll
            for (int nt = 0; nt < 2; ++nt) {
                const int o = ng * 32 + nt * 16 + (lane & 15);
                const float bfcv = bfc[o];
                #pragma unroll
                for (int r = 0; r < 4; ++r) {
                    const int idx = (m * 16 + (lane >> 4) * 4 + r) * 132 + o;
                    zbuf[idx] = fmaxf(zbuf[idx] + FCC[m][nt][r] + bfcv, 0.f);
                }
            }
    }
    __syncthreads();
    {
        const int s = t >> 4, l16 = t & 15, o0 = l16 * 8;
        const int b = b0 + s;
        const int item = item_id[b];
        const int user = user_id[b];
        const float* qp = Qp + (size_t)item * 256;
        const float* pu = Pmat + (size_t)user * 128;
        float acc2 = 0.f;
        #pragma unroll
        for (int i = 0; i < 8; ++i) acc2 = fmaf(zbuf[s * 132 + o0 + i], qp[o0 + i], acc2);
        #pragma unroll
        for (int i = 0; i < 8; ++i) acc2 = fmaf(pu[o0 + i], qp[128 + o0 + i], acc2);
        acc2 += __shfl_xor(acc2, 1, 16);
        acc2 += __shfl_xor(acc2, 2, 16);
        acc2 += __shfl_xor(acc2, 4, 16);
        acc2 += __shfl_xor(acc2, 8, 16);
        if (l16 == 0) out[b] = acc2 + b_item[item];
    }
}

extern "C" void kernel_launch(void* const* d_in, const int* in_sizes, int n_in,
                              void* d_out, int out_size, void* d_ws, size_t ws_size,
                              hipStream_t stream)
{
    const int*   user_id = (const int*)  d_in[0];
    const int*   seq     = (const int*)  d_in[1];
    const int*   item_id = (const int*)  d_in[2];
    const float* Q       = (const float*)d_in[3];
    const float* Pmat    = (const float*)d_in[4];
    const float* Qp      = (const float*)d_in[5];
    const float* b_item  = (const float*)d_in[6];
    const float* Wv      = (const float*)d_in[7];
    const float* bv      = (const float*)d_in[8];
    const float* Wh      = (const float*)d_in[9];
    const float* bh      = (const float*)d_in[10];
    const float* Wfc     = (const float*)d_in[11];
    const float* bfc     = (const float*)d_in[12];
    float* out = (float*)d_out;

    hipLaunchKernelGGL(caser_main, dim3(256), dim3(512), 0, stream,
                       user_id, seq, item_id, Q, Pmat, Qp, b_item,
                       Wv, bv, Wh, bh, Wfc, bfc, out);
}

// Round 8
// 108.135 us; speedup vs baseline: 44.8228x; 2.8104x over previous
//
#include <hip/hip_runtime.h>
#include <cstdint>
#include <cstddef>

typedef short bf16x8 __attribute__((ext_vector_type(8)));
typedef float f32x4  __attribute__((ext_vector_type(4)));

#define MFMA16(A, B, C) __builtin_amdgcn_mfma_f32_16x16x32_bf16(A, B, C, 0, 0, 0)

constexpr int XSTR = 1032;   // u16 row stride per sample strip (2064 B, 16B-aligned)
constexpr size_t WS_FC   = (size_t)2176 * 1024;           // packed Wfc frags
constexpr size_t WS_BOTH = WS_FC + (size_t)576 * 1024;    // + packed Wh frags

__device__ __forceinline__ unsigned short f2bf(float x) {
    unsigned u = __float_as_uint(x);
    unsigned r = u + 0x7fffu + ((u >> 16) & 1u);
    return (unsigned short)(r >> 16);
}
__device__ __forceinline__ float bf2f(unsigned short h) {
    return __uint_as_float(((unsigned)h) << 16);
}
__device__ __forceinline__ bf16x8 load8_f32(const float* __restrict__ s) {
    float4 a = *(const float4*)s;
    float4 b = *(const float4*)(s + 4);
    bf16x8 r;
    r[0]=(short)f2bf(a.x); r[1]=(short)f2bf(a.y); r[2]=(short)f2bf(a.z); r[3]=(short)f2bf(a.w);
    r[4]=(short)f2bf(b.x); r[5]=(short)f2bf(b.y); r[6]=(short)f2bf(b.z); r[7]=(short)f2bf(b.w);
    return r;
}

// FC B-frag (16x16x32): lane element j = Wfc[ntile*16+(lane&15)][kg*32+(lane>>4)*8+j]
// (direct form validated by R6/R7 pass; packed form = prep-stored output of the same)
template<int MODE>
__device__ __forceinline__ bf16x8 fc_bfrag(const unsigned short* __restrict__ wfcb,
                                           const float* __restrict__ Wfc,
                                           int kg, int ntile, int lane)
{
    if constexpr (MODE >= 1) {
        return *(const bf16x8*)(wfcb + (((size_t)(kg * 8 + ntile)) << 9) + lane * 8);
    } else {
        const float* s = Wfc + (size_t)(ntile * 16 + (lane & 15)) * 8704
                             + kg * 32 + (lane >> 4) * 8;
        return load8_f32(s);
    }
}
// hconv B-frag: k = kstep*32+(lane>>4)*8+j -> Wh[H-1][ntile*16+(lane&15)][k>>7][k&127]
template<int MODE>
__device__ __forceinline__ bf16x8 wh_bfrag(const unsigned short* __restrict__ whb,
                                           const float* __restrict__ Wh,
                                           int H, int kstep, int ntile, int lane)
{
    if constexpr (MODE == 2) {
        return *(const bf16x8*)(whb +
            (((size_t)(8 * H * (H - 1) + kstep * 4 + ntile)) << 9) + lane * 8);
    } else {
        const int k = kstep * 32 + (lane >> 4) * 8;
        const float* s = Wh + ((((size_t)(H - 1) * 64 + ntile * 16 + (lane & 15)) * 8
                               + (k >> 7)) * 128 + (k & 127));
        return load8_f32(s);
    }
}

// prep = run the direct loader once per frag, store result (packed == direct bit-identical)
__global__ __launch_bounds__(256)
void caser_prep(const float* __restrict__ Wfc, const float* __restrict__ Wh,
                unsigned short* __restrict__ wfcb, unsigned short* __restrict__ whb,
                int nfrag)
{
    const int tid = blockIdx.x * 256 + threadIdx.x;
    const int lane = tid & 63, frag = tid >> 6;
    if (frag >= nfrag) return;
    if (frag < 2176) {
        const int kg = frag >> 3, nt = frag & 7;
        bf16x8 v = fc_bfrag<0>(nullptr, Wfc, kg, nt, lane);
        *(bf16x8*)(wfcb + ((size_t)frag << 9) + lane * 8) = v;
    } else {
        const int f2 = frag - 2176;
        int h = 1;
        while (f2 >= 8 * h * (h + 1)) ++h;
        const int fl = f2 - 8 * h * (h - 1);
        const int nt = fl & 3, kstep = fl >> 2;
        bf16x8 v = wh_bfrag<0>(nullptr, Wh, h, kstep, nt, lane);
        *(bf16x8*)(whb + ((size_t)f2 << 9) + lane * 8) = v;
    }
}

// ===================== hconv MFMA (one h, one j-parity) ======================
// D[sample=(lane>>4)*4+r][filter_local=lane&15]  (m89 layout, R6/R7-validated)
template<int H, int PP, int MODE>
__device__ __forceinline__ void hconv_compute(
    const unsigned short* __restrict__ xs,
    const unsigned short* __restrict__ whb, const float* __restrict__ Wh,
    const float* __restrict__ bh,
    int m, int n2, int lane, int laneA, float mx[2][4])
{
    constexpr int NJ = 9 - H;
    constexpr int NJS = (PP == 0) ? ((NJ + 1) / 2) : (NJ / 2);
    if constexpr (NJS > 0) {
        f32x4 C[NJS][2] = {};
        const unsigned short* xbase = xs + m * 16 * XSTR + laneA;
        #pragma unroll
        for (int kstep = 0; kstep < 4 * H; ++kstep) {
            const int hp = kstep >> 2, d0 = (kstep & 3) * 32;
            bf16x8 B0 = wh_bfrag<MODE>(whb, Wh, H, kstep, n2 * 2,     lane);
            bf16x8 B1 = wh_bfrag<MODE>(whb, Wh, H, kstep, n2 * 2 + 1, lane);
            #pragma unroll
            for (int idx = 0; idx < NJS; ++idx) {
                const int j = PP + 2 * idx;
                bf16x8 A = *(const bf16x8*)(xbase + (j + hp) * 128 + d0);
                C[idx][0] = MFMA16(A, B0, C[idx][0]);
                C[idx][1] = MFMA16(A, B1, C[idx][1]);
            }
        }
        #pragma unroll
        for (int nt = 0; nt < 2; ++nt) {
            const float bhv = bh[(H - 1) * 64 + n2 * 32 + nt * 16 + (lane & 15)];
            #pragma unroll
            for (int idx = 0; idx < NJS; ++idx)
                #pragma unroll
                for (int r = 0; r < 4; ++r)
                    mx[nt][r] = fmaxf(mx[nt][r], fmaxf(C[idx][nt][r] + bhv, 0.f));
        }
    }
}

// one full h-step: hconv MFMA -> parity merge -> feat chunk -> FC accumulate
template<int H, int MODE>
__device__ __forceinline__ void hstep(
    const unsigned short* __restrict__ xs, unsigned short* __restrict__ feat,
    float* __restrict__ cand,
    const unsigned short* __restrict__ whb, const unsigned short* __restrict__ wfcb,
    const float* __restrict__ Wh, const float* __restrict__ Wfc,
    const float* __restrict__ bh,
    int t, int lane, int laneA, int w, f32x4 (&FCC)[2][2])
{
    const int hm = w & 1, hn2 = (w >> 1) & 1, pj = w >> 2;
    const int kh = w & 1, ng = w >> 1;
    float mx[2][4] = {};
    if (pj == 0) hconv_compute<H, 0, MODE>(xs, whb, Wh, bh, hm, hn2, lane, laneA, mx);
    else         hconv_compute<H, 1, MODE>(xs, whb, Wh, bh, hm, hn2, lane, laneA, mx);
    #pragma unroll
    for (int nt = 0; nt < 2; ++nt)
        #pragma unroll
        for (int r = 0; r < 4; ++r)
            cand[pj * 2176 + (hm * 16 + (lane >> 4) * 4 + r) * 68 +
                 hn2 * 32 + nt * 16 + (lane & 15)] = mx[nt][r];
    __syncthreads();
    {   // merge 2 parity candidates -> bf16 feat chunk [32][64]
        const int s = t >> 4, f0 = (t & 15) * 4;
        float4 a = *(const float4*)&cand[s * 68 + f0];
        float4 b = *(const float4*)&cand[2176 + s * 68 + f0];
        uint2 pk;
        pk.x = (unsigned)f2bf(fmaxf(a.x, b.x)) | ((unsigned)f2bf(fmaxf(a.y, b.y)) << 16);
        pk.y = (unsigned)f2bf(fmaxf(a.z, b.z)) | ((unsigned)f2bf(fmaxf(a.w, b.w)) << 16);
        *(uint2*)(feat + s * XSTR + f0) = pk;
    }
    __syncthreads();
    {   // FC on this 64-wide K chunk: kg = 256 + (H-1)*2 + kh
        const int kg = 256 + (H - 1) * 2 + kh;
        bf16x8 B0 = fc_bfrag<MODE>(wfcb, Wfc, kg, ng * 2,     lane);
        bf16x8 B1 = fc_bfrag<MODE>(wfcb, Wfc, kg, ng * 2 + 1, lane);
        bf16x8 A0 = *(const bf16x8*)(feat + laneA + kh * 32);
        bf16x8 A1 = *(const bf16x8*)(feat + 16 * XSTR + laneA + kh * 32);
        FCC[0][0] = MFMA16(A0, B0, FCC[0][0]);
        FCC[0][1] = MFMA16(A0, B1, FCC[0][1]);
        FCC[1][0] = MFMA16(A1, B0, FCC[1][0]);
        FCC[1][1] = MFMA16(A1, B1, FCC[1][1]);
    }
    __syncthreads();   // protect cand for next step / zbuf reuse
}

// ============================ main fused kernel ==============================
template<int MODE>
__global__ __launch_bounds__(512, 1)
void caser_main(const int* __restrict__ user_id,
                const int* __restrict__ seq,
                const int* __restrict__ item_id,
                const float* __restrict__ Q,
                const float* __restrict__ Pmat,
                const float* __restrict__ Qp,
                const float* __restrict__ b_item,
                const float* __restrict__ Wv,
                const float* __restrict__ bv,
                const float* __restrict__ Wh,
                const float* __restrict__ bh,
                const float* __restrict__ Wfc,
                const float* __restrict__ bfc,
                const unsigned short* __restrict__ wfcb,
                const unsigned short* __restrict__ whb,
                float* __restrict__ out)
{
    __shared__ unsigned short xs[32 * XSTR];     // 66048 B  x = Q[seq], bf16
    __shared__ unsigned short feat[32 * XSTR];   // 66048 B  FC A-operand chunks
    __shared__ float cand[2 * 32 * 68];          // 17408 B  hconv cands / zbuf
    __shared__ float wv_s[576];                  //  2304 B  Wv + bv

    const int t = threadIdx.x;
    const int lane = t & 63;
    const int w = t >> 6;
    const int b0 = blockIdx.x * 32;
    const int laneA = (lane & 15) * XSTR + (lane >> 4) * 8;

    // ---------------- phase 0: weights + x gather ----------------
    // (R6 bugfix retained: strided loop covers all 576 entries)
    for (int idx = t; idx < 576; idx += 512)
        wv_s[idx] = (idx < 512) ? Wv[idx] : bv[idx - 512];
    {
        const int r = t >> 1, half = t & 1;
        const int s = r >> 3, l = r & 7;
        const int it = seq[(b0 + s) * 8 + l];
        const float4* src = (const float4*)(Q + (size_t)it * 128 + half * 64);
        unsigned short* dst = xs + s * XSTR + l * 128 + half * 64;
        #pragma unroll
        for (int i = 0; i < 16; ++i) {
            float4 v = src[i];
            uint2 pk;
            pk.x = (unsigned)f2bf(v.x) | ((unsigned)f2bf(v.y) << 16);
            pk.y = (unsigned)f2bf(v.z) | ((unsigned)f2bf(v.w) << 16);
            *(uint2*)(dst + i * 4) = pk;
        }
    }
    __syncthreads();

    // vconv x slice -> regs: thread (sv=t&31, dq=t>>5) owns d = dq*8..+7
    const int sv = t & 31, dq = t >> 5;
    float xr[8][8];
    #pragma unroll
    for (int l = 0; l < 8; ++l) {
        bf16x8 v = *(const bf16x8*)(xs + sv * XSTR + l * 128 + dq * 8);
        #pragma unroll
        for (int i = 0; i < 8; ++i) xr[l][i] = bf2f((unsigned short)v[i]);
    }

    f32x4 FCC[2][2] = {};
    const int kh = w & 1, ng = w >> 1;

    // ---------------- phase 1: vconv + FC (k = 0..8191) ----------------
    for (int c = 0; c < 8; ++c) {
        #pragma unroll
        for (int fl = 0; fl < 8; ++fl) {
            const int f = c * 8 + fl;
            const float bvv = wv_s[512 + f];
            float acc[8];
            #pragma unroll
            for (int i = 0; i < 8; ++i) acc[i] = bvv;
            #pragma unroll
            for (int l = 0; l < 8; ++l) {
                const float wl = wv_s[f * 8 + l];
                #pragma unroll
                for (int i = 0; i < 8; ++i) acc[i] = fmaf(xr[l][i], wl, acc[i]);
            }
            uint4 pk;
            pk.x = (unsigned)f2bf(fmaxf(acc[0], 0.f)) | ((unsigned)f2bf(fmaxf(acc[1], 0.f)) << 16);
            pk.y = (unsigned)f2bf(fmaxf(acc[2], 0.f)) | ((unsigned)f2bf(fmaxf(acc[3], 0.f)) << 16);
            pk.z = (unsigned)f2bf(fmaxf(acc[4], 0.f)) | ((unsigned)f2bf(fmaxf(acc[5], 0.f)) << 16);
            pk.w = (unsigned)f2bf(fmaxf(acc[6], 0.f)) | ((unsigned)f2bf(fmaxf(acc[7], 0.f)) << 16);
            *(uint4*)(feat + sv * XSTR + fl * 128 + dq * 8) = pk;
        }
        __syncthreads();
        #pragma unroll
        for (int ks = 0; ks < 16; ++ks) {
            const int kl = kh * 16 + ks;
            const int kg = c * 32 + kl;
            bf16x8 B0 = fc_bfrag<MODE>(wfcb, Wfc, kg, ng * 2,     lane);
            bf16x8 B1 = fc_bfrag<MODE>(wfcb, Wfc, kg, ng * 2 + 1, lane);
            bf16x8 A0 = *(const bf16x8*)(feat + laneA + kl * 32);
            bf16x8 A1 = *(const bf16x8*)(feat + 16 * XSTR + laneA + kl * 32);
            FCC[0][0] = MFMA16(A0, B0, FCC[0][0]);
            FCC[0][1] = MFMA16(A0, B1, FCC[0][1]);
            FCC[1][0] = MFMA16(A1, B0, FCC[1][0]);
            FCC[1][1] = MFMA16(A1, B1, FCC[1][1]);
        }
        __syncthreads();
    }

    // ---------------- phase 2: MFMA hconv h=1..8 + FC (k = 8192..8703) ----
    hstep<1, MODE>(xs, feat, cand, whb, wfcb, Wh, Wfc, bh, t, lane, laneA, w, FCC);
    hstep<2, MODE>(xs, feat, cand, whb, wfcb, Wh, Wfc, bh, t, lane, laneA, w, FCC);
    hstep<3, MODE>(xs, feat, cand, whb, wfcb, Wh, Wfc, bh, t, lane, laneA, w, FCC);
    hstep<4, MODE>(xs, feat, cand, whb, wfcb, Wh, Wfc, bh, t, lane, laneA, w, FCC);
    hstep<5, MODE>(xs, feat, cand, whb, wfcb, Wh, Wfc, bh, t, lane, laneA, w, FCC);
    hstep<6, MODE>(xs, feat, cand, whb, wfcb, Wh, Wfc, bh, t, lane, laneA, w, FCC);
    hstep<7, MODE>(xs, feat, cand, whb, wfcb, Wh, Wfc, bh, t, lane, laneA, w, FCC);
    hstep<8, MODE>(xs, feat, cand, whb, wfcb, Wh, Wfc, bh, t, lane, laneA, w, FCC);

    // ---------------- epilogue: merge K-halves, relu, score --------------
    float* zbuf = cand;   // [32][132]
    if (kh == 1) {
        #pragma unroll
        for (int m = 0; m < 2; ++m)
            #pragma unroll
            for (int nt = 0; nt < 2; ++nt)
                #pragma unroll
                for (int r = 0; r < 4; ++r)
                    zbuf[(m * 16 + (lane >> 4) * 4 + r) * 132 +
                         ng * 32 + nt * 16 + (lane & 15)] = FCC[m][nt][r];
    }
    __syncthreads();
    if (kh == 0) {
        #pragma unroll
        for (int m = 0; m < 2; ++m)
            #pragma unroll
            for (int nt = 0; nt < 2; ++nt) {
                const int o = ng * 32 + nt * 16 + (lane & 15);
                const float bfcv = bfc[o];
                #pragma unroll
                for (int r = 0; r < 4; ++r) {
                    const int idx = (m * 16 + (lane >> 4) * 4 + r) * 132 + o;
                    zbuf[idx] = fmaxf(zbuf[idx] + FCC[m][nt][r] + bfcv, 0.f);
                }
            }
    }
    __syncthreads();
    {
        const int s = t >> 4, l16 = t & 15, o0 = l16 * 8;
        const int b = b0 + s;
        const int item = item_id[b];
        const int user = user_id[b];
        const float* qp = Qp + (size_t)item * 256;
        const float* pu = Pmat + (size_t)user * 128;
        float acc2 = 0.f;
        #pragma unroll
        for (int i = 0; i < 8; ++i) acc2 = fmaf(zbuf[s * 132 + o0 + i], qp[o0 + i], acc2);
        #pragma unroll
        for (int i = 0; i < 8; ++i) acc2 = fmaf(pu[o0 + i], qp[128 + o0 + i], acc2);
        acc2 += __shfl_xor(acc2, 1, 16);
        acc2 += __shfl_xor(acc2, 2, 16);
        acc2 += __shfl_xor(acc2, 4, 16);
        acc2 += __shfl_xor(acc2, 8, 16);
        if (l16 == 0) out[b] = acc2 + b_item[item];
    }
}

extern "C" void kernel_launch(void* const* d_in, const int* in_sizes, int n_in,
                              void* d_out, int out_size, void* d_ws, size_t ws_size,
                              hipStream_t stream)
{
    const int*   user_id = (const int*)  d_in[0];
    const int*   seq     = (const int*)  d_in[1];
    const int*   item_id = (const int*)  d_in[2];
    const float* Q       = (const float*)d_in[3];
    const float* Pmat    = (const float*)d_in[4];
    const float* Qp      = (const float*)d_in[5];
    const float* b_item  = (const float*)d_in[6];
    const float* Wv      = (const float*)d_in[7];
    const float* bv      = (const float*)d_in[8];
    const float* Wh      = (const float*)d_in[9];
    const float* bh      = (const float*)d_in[10];
    const float* Wfc     = (const float*)d_in[11];
    const float* bfc     = (const float*)d_in[12];
    float* out = (float*)d_out;

    unsigned short* wfcb = (unsigned short*)d_ws;
    unsigned short* whb  = wfcb + WS_FC / 2;

    if (ws_size >= WS_BOTH) {
        hipLaunchKernelGGL(caser_prep, dim3(688), dim3(256), 0, stream,
                           Wfc, Wh, wfcb, whb, 2752);
        hipLaunchKernelGGL((caser_main<2>), dim3(256), dim3(512), 0, stream,
                           user_id, seq, item_id, Q, Pmat, Qp, b_item,
                           Wv, bv, Wh, bh, Wfc, bfc, wfcb, whb, out);
    } else if (ws_size >= WS_FC) {
        hipLaunchKernelGGL(caser_prep, dim3(544), dim3(256), 0, stream,
                           Wfc, Wh, wfcb, whb, 2176);
        hipLaunchKernelGGL((caser_main<1>), dim3(256), dim3(512), 0, stream,
                           user_id, seq, item_id, Q, Pmat, Qp, b_item,
                           Wv, bv, Wh, bh, Wfc, bfc, wfcb, whb, out);
    } else {
        hipLaunchKernelGGL((caser_main<0>), dim3(256), dim3(512), 0, stream,
                           user_id, seq, item_id, Q, Pmat, Qp, b_item,
                           Wv, bv, Wh, bh, Wfc, bfc,
                           (const unsigned short*)nullptr, (const unsigned short*)nullptr, out);
    }
}

// Round 10
// 92.848 us; speedup vs baseline: 52.2026x; 1.1646x over previous
//
#include <hip/hip_runtime.h>
#include <hip/hip_bf16.h>
#include <cstdint>
#include <cstddef>

typedef short bf16x8 __attribute__((ext_vector_type(8)));
typedef float f32x4  __attribute__((ext_vector_type(4)));

#define MFMA16(A, B, C) __builtin_amdgcn_mfma_f32_16x16x32_bf16(A, B, C, 0, 0, 0)

constexpr int XSTR = 1032;   // u16 row stride per sample strip in xs (2064 B)
constexpr int BSTR = 520;    // u16 per-sample stride in fbuf (1040 B, 16B-aligned)
constexpr size_t WS_FC   = (size_t)2176 * 1024;
constexpr size_t WS_BOTH = WS_FC + (size_t)576 * 1024;

__device__ __forceinline__ unsigned short f2bf(float x) {
    unsigned u = __float_as_uint(x);
    unsigned r = u + 0x7fffu + ((u >> 16) & 1u);
    return (unsigned short)(r >> 16);
}
__device__ __forceinline__ float bf2f(unsigned short h) {
    return __uint_as_float(((unsigned)h) << 16);
}
// hardware v_cvt_pk_bf16_f32 (RNE) — same rounding as f2bf
__device__ __forceinline__ unsigned pkbf(float a, float b) {
    __hip_bfloat162 h = __float22bfloat162_rn(make_float2(a, b));
    return *reinterpret_cast<unsigned*>(&h);
}
__device__ __forceinline__ bf16x8 load8_f32(const float* __restrict__ s) {
    float4 a = *(const float4*)s;
    float4 b = *(const float4*)(s + 4);
    bf16x8 r;
    r[0]=(short)f2bf(a.x); r[1]=(short)f2bf(a.y); r[2]=(short)f2bf(a.z); r[3]=(short)f2bf(a.w);
    r[4]=(short)f2bf(b.x); r[5]=(short)f2bf(b.y); r[6]=(short)f2bf(b.z); r[7]=(short)f2bf(b.w);
    return r;
}

// FC B-frag: lane element j = Wfc[ntile*16+(lane&15)][kg*32+(lane>>4)*8+j]
template<int MODE>
__device__ __forceinline__ bf16x8 fc_bfrag(const unsigned short* __restrict__ wfcb,
                                           const float* __restrict__ Wfc,
                                           int kg, int ntile, int lane)
{
    if constexpr (MODE >= 1) {
        return *(const bf16x8*)(wfcb + (((size_t)(kg * 8 + ntile)) << 9) + lane * 8);
    } else {
        const float* s = Wfc + (size_t)(ntile * 16 + (lane & 15)) * 8704
                             + kg * 32 + (lane >> 4) * 8;
        return load8_f32(s);
    }
}
// hconv B-frag: k = kstep*32+(lane>>4)*8+j -> Wh[H-1][ntile*16+(lane&15)][k>>7][k&127]
template<int MODE>
__device__ __forceinline__ bf16x8 wh_bfrag(const unsigned short* __restrict__ whb,
                                           const float* __restrict__ Wh,
                                           int H, int kstep, int ntile, int lane)
{
    if constexpr (MODE == 2) {
        return *(const bf16x8*)(whb +
            (((size_t)(8 * H * (H - 1) + kstep * 4 + ntile)) << 9) + lane * 8);
    } else {
        const int k = kstep * 32 + (lane >> 4) * 8;
        const float* s = Wh + ((((size_t)(H - 1) * 64 + ntile * 16 + (lane & 15)) * 8
                               + (k >> 7)) * 128 + (k & 127));
        return load8_f32(s);
    }
}

// prep = run the direct loader once per frag, store result (packed == direct)
__global__ __launch_bounds__(256)
void caser_prep(const float* __restrict__ Wfc, const float* __restrict__ Wh,
                unsigned short* __restrict__ wfcb, unsigned short* __restrict__ whb,
                int nfrag)
{
    const int tid = blockIdx.x * 256 + threadIdx.x;
    const int lane = tid & 63, frag = tid >> 6;
    if (frag >= nfrag) return;
    if (frag < 2176) {
        const int kg = frag >> 3, nt = frag & 7;
        bf16x8 v = fc_bfrag<0>(nullptr, Wfc, kg, nt, lane);
        *(bf16x8*)(wfcb + ((size_t)frag << 9) + lane * 8) = v;
    } else {
        const int f2 = frag - 2176;
        int h = 1;
        while (f2 >= 8 * h * (h + 1)) ++h;
        const int fl = f2 - 8 * h * (h - 1);
        const int nt = fl & 3, kstep = fl >> 2;
        bf16x8 v = wh_bfrag<0>(nullptr, Wh, h, kstep, nt, lane);
        *(bf16x8*)(whb + ((size_t)f2 << 9) + lane * 8) = v;
    }
}

// ===================== hconv MFMA (one h, one j-parity) ======================
// D[sample=(lane>>4)*4+r][filter_local=lane&15]  (R6-R8 validated)
template<int H, int PP, int MODE>
__device__ __forceinline__ void hconv_compute(
    const unsigned short* __restrict__ xs,
    const unsigned short* __restrict__ whb, const float* __restrict__ Wh,
    const float* __restrict__ bh,
    int m, int n2, int lane, int laneA, float mx[2][4])
{
    constexpr int NJ = 9 - H;
    constexpr int NJS = (PP == 0) ? ((NJ + 1) / 2) : (NJ / 2);
    if constexpr (NJS > 0) {
        f32x4 C[NJS][2] = {};
        const unsigned short* xbase = xs + m * 16 * XSTR + laneA;
        #pragma unroll
        for (int kstep = 0; kstep < 4 * H; ++kstep) {
            const int hp = kstep >> 2, d0 = (kstep & 3) * 32;
            bf16x8 B0 = wh_bfrag<MODE>(whb, Wh, H, kstep, n2 * 2,     lane);
            bf16x8 B1 = wh_bfrag<MODE>(whb, Wh, H, kstep, n2 * 2 + 1, lane);
            #pragma unroll
            for (int idx = 0; idx < NJS; ++idx) {
                const int j = PP + 2 * idx;
                bf16x8 A = *(const bf16x8*)(xbase + (j + hp) * 128 + d0);
                C[idx][0] = MFMA16(A, B0, C[idx][0]);
                C[idx][1] = MFMA16(A, B1, C[idx][1]);
            }
        }
        #pragma unroll
        for (int nt = 0; nt < 2; ++nt) {
            const float bhv = bh[(H - 1) * 64 + n2 * 32 + nt * 16 + (lane & 15)];
            #pragma unroll
            for (int idx = 0; idx < NJS; ++idx)
                #pragma unroll
                for (int r = 0; r < 4; ++r)
                    mx[nt][r] = fmaxf(mx[nt][r], fmaxf(C[idx][nt][r] + bhv, 0.f));
        }
    }
}

// one full h-step: hconv MFMA -> parity merge -> feat chunk (fbuf0) -> FC
template<int H, int MODE>
__device__ __forceinline__ void hstep(
    const unsigned short* __restrict__ xs, unsigned short* __restrict__ fb0,
    float* __restrict__ cand,
    const unsigned short* __restrict__ whb, const unsigned short* __restrict__ wfcb,
    const float* __restrict__ Wh, const float* __restrict__ Wfc,
    const float* __restrict__ bh,
    int t, int lane, int laneA, int laneB, int w, f32x4 (&FCC)[2][2])
{
    const int hm = w & 1, hn2 = (w >> 1) & 1, pj = w >> 2;
    const int kh = w & 1, ng = w >> 1;
    float mx[2][4] = {};
    if (pj == 0) hconv_compute<H, 0, MODE>(xs, whb, Wh, bh, hm, hn2, lane, laneA, mx);
    else         hconv_compute<H, 1, MODE>(xs, whb, Wh, bh, hm, hn2, lane, laneA, mx);
    #pragma unroll
    for (int nt = 0; nt < 2; ++nt)
        #pragma unroll
        for (int r = 0; r < 4; ++r)
            cand[pj * 2176 + (hm * 16 + (lane >> 4) * 4 + r) * 68 +
                 hn2 * 32 + nt * 16 + (lane & 15)] = mx[nt][r];
    __syncthreads();
    {   // merge 2 parity candidates -> bf16 feat chunk [32][64] in fbuf0
        const int s = t >> 4, f0 = (t & 15) * 4;
        float4 a = *(const float4*)&cand[s * 68 + f0];
        float4 b = *(const float4*)&cand[2176 + s * 68 + f0];
        uint2 pk;
        pk.x = pkbf(fmaxf(a.x, b.x), fmaxf(a.y, b.y));
        pk.y = pkbf(fmaxf(a.z, b.z), fmaxf(a.w, b.w));
        *(uint2*)(fb0 + s * BSTR + f0) = pk;
    }
    __syncthreads();
    {   // FC on this 64-wide K chunk: kg = 256 + (H-1)*2 + kh
        const int kg = 256 + (H - 1) * 2 + kh;
        bf16x8 B0 = fc_bfrag<MODE>(wfcb, Wfc, kg, ng * 2,     lane);
        bf16x8 B1 = fc_bfrag<MODE>(wfcb, Wfc, kg, ng * 2 + 1, lane);
        bf16x8 A0 = *(const bf16x8*)(fb0 + laneB + kh * 32);
        bf16x8 A1 = *(const bf16x8*)(fb0 + 16 * BSTR + laneB + kh * 32);
        FCC[0][0] = MFMA16(A0, B0, FCC[0][0]);
        FCC[0][1] = MFMA16(A0, B1, FCC[0][1]);
        FCC[1][0] = MFMA16(A1, B0, FCC[1][0]);
        FCC[1][1] = MFMA16(A1, B1, FCC[1][1]);
    }
    __syncthreads();   // protect cand for next step / zbuf reuse
}

// ============================ main fused kernel ==============================
template<int MODE>
__global__ __launch_bounds__(512, 1)
void caser_main(const int* __restrict__ user_id,
                const int* __restrict__ seq,
                const int* __restrict__ item_id,
                const float* __restrict__ Q,
                const float* __restrict__ Pmat,
                const float* __restrict__ Qp,
                const float* __restrict__ b_item,
                const float* __restrict__ Wv,
                const float* __restrict__ bv,
                const float* __restrict__ Wh,
                const float* __restrict__ bh,
                const float* __restrict__ Wfc,
                const float* __restrict__ bfc,
                const unsigned short* __restrict__ wfcb,
                const unsigned short* __restrict__ whb,
                float* __restrict__ out)
{
    __shared__ unsigned short xs[32 * XSTR];       // 66048 B  x = Q[seq], bf16
    __shared__ unsigned short fbuf[2 * 32 * BSTR]; // 66560 B  ping-pong A-chunks
    __shared__ float cand[2 * 32 * 68];            // 17408 B  hconv cands / zbuf
    __shared__ float wv_s[576];                    //  2304 B  Wv + bv

    const int t = threadIdx.x;
    const int lane = t & 63;
    const int w = t >> 6;
    const int b0 = blockIdx.x * 32;
    const int laneA = (lane & 15) * XSTR + (lane >> 4) * 8;
    const int laneB = (lane & 15) * BSTR + (lane >> 4) * 8;

    // ---------------- phase 0: weights + x gather ----------------
    for (int idx = t; idx < 576; idx += 512)
        wv_s[idx] = (idx < 512) ? Wv[idx] : bv[idx - 512];
    // lane-contiguous 16B chunks: coalesced global reads, conflict-free LDS writes
    // decode (BUGFIX vs R9): 32 float4-chunks per 128-wide row; s = idx>>8 (0..31)
    #pragma unroll 4
    for (int k = 0; k < 16; ++k) {
        const int idx = t + k * 512;        // 0..8191 chunks of 4 floats
        const int i = idx & 31;             // float4-chunk within row
        const int l = (idx >> 5) & 7;
        const int s = idx >> 8;
        const int it = seq[(b0 + s) * 8 + l];
        float4 v = *(const float4*)(Q + (size_t)it * 128 + i * 4);
        uint2 pk;
        pk.x = pkbf(v.x, v.y);
        pk.y = pkbf(v.z, v.w);
        *(uint2*)(xs + s * XSTR + l * 128 + i * 4) = pk;
    }
    __syncthreads();

    // vconv x slice -> regs: thread (sv=t&31, dq=t>>5) owns d = dq*8..+7
    const int sv = t & 31, dq = t >> 5;
    float xr[8][8];
    #pragma unroll
    for (int l = 0; l < 8; ++l) {
        bf16x8 v = *(const bf16x8*)(xs + sv * XSTR + l * 128 + dq * 8);
        #pragma unroll
        for (int i = 0; i < 8; ++i) xr[l][i] = bf2f((unsigned short)v[i]);
    }

    f32x4 FCC[2][2] = {};
    const int kh = w & 1, ng = w >> 1;

    // ---------------- phase 1: vconv ∥ FC, ping-pong (k = 0..8191) --------
    // half-chunk hc = 4 features = K 512. vconv(hc+1) overlaps FC(hc).
    uint4 vc[4];
    #define VCONV_HALF(hc_, dst_)                                              \
        {                                                                      \
            _Pragma("unroll")                                                  \
            for (int fl = 0; fl < 4; ++fl) {                                   \
                const int f = (hc_) * 4 + fl;                                  \
                const float bvv = wv_s[512 + f];                               \
                float acc[8];                                                  \
                _Pragma("unroll")                                              \
                for (int i = 0; i < 8; ++i) acc[i] = bvv;                      \
                _Pragma("unroll")                                              \
                for (int l = 0; l < 8; ++l) {                                  \
                    const float wl = wv_s[f * 8 + l];                          \
                    _Pragma("unroll")                                          \
                    for (int i = 0; i < 8; ++i)                                \
                        acc[i] = fmaf(xr[l][i], wl, acc[i]);                   \
                }                                                              \
                dst_[fl].x = pkbf(fmaxf(acc[0], 0.f), fmaxf(acc[1], 0.f));     \
                dst_[fl].y = pkbf(fmaxf(acc[2], 0.f), fmaxf(acc[3], 0.f));     \
                dst_[fl].z = pkbf(fmaxf(acc[4], 0.f), fmaxf(acc[5], 0.f));     \
                dst_[fl].w = pkbf(fmaxf(acc[6], 0.f), fmaxf(acc[7], 0.f));     \
            }                                                                  \
        }
    #define VSTORE(buf_, dst_)                                                 \
        {                                                                      \
            unsigned short* fb = fbuf + (buf_) * (32 * BSTR);                  \
            _Pragma("unroll")                                                  \
            for (int fl = 0; fl < 4; ++fl)                                     \
                *(uint4*)(fb + sv * BSTR + fl * 128 + dq * 8) = vc[fl];        \
        }

    VCONV_HALF(0, vc);
    VSTORE(0, vc);
    __syncthreads();

    #pragma unroll 2
    for (int hc = 0; hc < 16; ++hc) {
        uint4 nxt[4];
        if (hc < 15) VCONV_HALF(hc + 1, nxt);
        {   // FC on buf hc&1 (K=512): kl = kh*8+ks, kg = hc*16+kl
            const unsigned short* fb = fbuf + (hc & 1) * (32 * BSTR);
            #pragma unroll
            for (int ks = 0; ks < 8; ++ks) {
                const int kl = kh * 8 + ks;
                const int kg = hc * 16 + kl;
                bf16x8 B0 = fc_bfrag<MODE>(wfcb, Wfc, kg, ng * 2,     lane);
                bf16x8 B1 = fc_bfrag<MODE>(wfcb, Wfc, kg, ng * 2 + 1, lane);
                bf16x8 A0 = *(const bf16x8*)(fb + laneB + kl * 32);
                bf16x8 A1 = *(const bf16x8*)(fb + 16 * BSTR + laneB + kl * 32);
                FCC[0][0] = MFMA16(A0, B0, FCC[0][0]);
                FCC[0][1] = MFMA16(A0, B1, FCC[0][1]);
                FCC[1][0] = MFMA16(A1, B0, FCC[1][0]);
                FCC[1][1] = MFMA16(A1, B1, FCC[1][1]);
            }
        }
        if (hc < 15) {
            #pragma unroll
            for (int fl = 0; fl < 4; ++fl) vc[fl] = nxt[fl];
            VSTORE((hc + 1) & 1, vc);
        }
        __syncthreads();
    }
    #undef VCONV_HALF
    #undef VSTORE

    // ---------------- phase 2: MFMA hconv h=1..8 + FC (k = 8192..8703) ----
    unsigned short* fb0 = fbuf;
    hstep<1, MODE>(xs, fb0, cand, whb, wfcb, Wh, Wfc, bh, t, lane, laneA, laneB, w, FCC);
    hstep<2, MODE>(xs, fb0, cand, whb, wfcb, Wh, Wfc, bh, t, lane, laneA, laneB, w, FCC);
    hstep<3, MODE>(xs, fb0, cand, whb, wfcb, Wh, Wfc, bh, t, lane, laneA, laneB, w, FCC);
    hstep<4, MODE>(xs, fb0, cand, whb, wfcb, Wh, Wfc, bh, t, lane, laneA, laneB, w, FCC);
    hstep<5, MODE>(xs, fb0, cand, whb, wfcb, Wh, Wfc, bh, t, lane, laneA, laneB, w, FCC);
    hstep<6, MODE>(xs, fb0, cand, whb, wfcb, Wh, Wfc, bh, t, lane, laneA, laneB, w, FCC);
    hstep<7, MODE>(xs, fb0, cand, whb, wfcb, Wh, Wfc, bh, t, lane, laneA, laneB, w, FCC);
    hstep<8, MODE>(xs, fb0, cand, whb, wfcb, Wh, Wfc, bh, t, lane, laneA, laneB, w, FCC);

    // ---------------- epilogue: merge K-halves, relu, score --------------
    float* zbuf = cand;   // [32][132]
    if (kh == 1) {
        #pragma unroll
        for (int m = 0; m < 2; ++m)
            #pragma unroll
            for (int nt = 0; nt < 2; ++nt)
                #pragma unroll
                for (int r = 0; r < 4; ++r)
                    zbuf[(m * 16 + (lane >> 4) * 4 + r) * 132 +
                         ng * 32 + nt * 16 + (lane & 15)] = FCC[m][nt][r];
    }
    __syncthreads();
    if (kh == 0) {
        #pragma unroll
        for (int m = 0; m < 2; ++m)
            #pragma unroll
            for (int nt = 0; nt < 2; ++nt) {
                const int o = ng * 32 + nt * 16 + (lane & 15);
                const float bfcv = bfc[o];
                #pragma unroll
                for (int r = 0; r < 4; ++r) {
                    const int idx = (m * 16 + (lane >> 4) * 4 + r) * 132 + o;
                    zbuf[idx] = fmaxf(zbuf[idx] + FCC[m][nt][r] + bfcv, 0.f);
                }
            }
    }
    __syncthreads();
    {
        const int s = t >> 4, l16 = t & 15, o0 = l16 * 8;
        const int b = b0 + s;
        const int item = item_id[b];
        const int user = user_id[b];
        const float* qp = Qp + (size_t)item * 256;
        const float* pu = Pmat + (size_t)user * 128;
        float acc2 = 0.f;
        #pragma unroll
        for (int i = 0; i < 8; ++i) acc2 = fmaf(zbuf[s * 132 + o0 + i], qp[o0 + i], acc2);
        #pragma unroll
        for (int i = 0; i < 8; ++i) acc2 = fmaf(pu[o0 + i], qp[128 + o0 + i], acc2);
        acc2 += __shfl_xor(acc2, 1, 16);
        acc2 += __shfl_xor(acc2, 2, 16);
        acc2 += __shfl_xor(acc2, 4, 16);
        acc2 += __shfl_xor(acc2, 8, 16);
        if (l16 == 0) out[b] = acc2 + b_item[item];
    }
}

extern "C" void kernel_launch(void* const* d_in, const int* in_sizes, int n_in,
                              void* d_out, int out_size, void* d_ws, size_t ws_size,
                              hipStream_t stream)
{
    const int*   user_id = (const int*)  d_in[0];
    const int*   seq     = (const int*)  d_in[1];
    const int*   item_id = (const int*)  d_in[2];
    const float* Q       = (const float*)d_in[3];
    const float* Pmat    = (const float*)d_in[4];
    const float* Qp      = (const float*)d_in[5];
    const float* b_item  = (const float*)d_in[6];
    const float* Wv      = (const float*)d_in[7];
    const float* bv      = (const float*)d_in[8];
    const float* Wh      = (const float*)d_in[9];
    const float* bh      = (const float*)d_in[10];
    const float* Wfc     = (const float*)d_in[11];
    const float* bfc     = (const float*)d_in[12];
    float* out = (float*)d_out;

    unsigned short* wfcb = (unsigned short*)d_ws;
    unsigned short* whb  = wfcb + WS_FC / 2;

    if (ws_size >= WS_BOTH) {
        hipLaunchKernelGGL(caser_prep, dim3(688), dim3(256), 0, stream,
                           Wfc, Wh, wfcb, whb, 2752);
        hipLaunchKernelGGL((caser_main<2>), dim3(256), dim3(512), 0, stream,
                           user_id, seq, item_id, Q, Pmat, Qp, b_item,
                           Wv, bv, Wh, bh, Wfc, bfc, wfcb, whb, out);
    } else if (ws_size >= WS_FC) {
        hipLaunchKernelGGL(caser_prep, dim3(544), dim3(256), 0, stream,
                           Wfc, Wh, wfcb, whb, 2176);
        hipLaunchKernelGGL((caser_main<1>), dim3(256), dim3(512), 0, stream,
                           user_id, seq, item_id, Q, Pmat, Qp, b_item,
                           Wv, bv, Wh, bh, Wfc, bfc, wfcb, whb, out);
    } else {
        hipLaunchKernelGGL((caser_main<0>), dim3(256), dim3(512), 0, stream,
                           user_id, seq, item_id, Q, Pmat, Qp, b_item,
                           Wv, bv, Wh, bh, Wfc, bfc,
                           (const unsigned short*)nullptr, (const unsigned short*)nullptr, out);
    }
}

// Round 11
// 85.873 us; speedup vs baseline: 56.4429x; 1.0812x over previous
//
#include <hip/hip_runtime.h>
#include <hip/hip_bf16.h>
#include <cstdint>
#include <cstddef>

typedef short bf16x8 __attribute__((ext_vector_type(8)));
typedef short bf16x4 __attribute__((ext_vector_type(4)));
typedef float f32x4  __attribute__((ext_vector_type(4)));

#define MFMA16(A, B, C) __builtin_amdgcn_mfma_f32_16x16x32_bf16(A, B, C, 0, 0, 0)

constexpr int XSTR = 1032;   // u16 row stride per sample strip in xs (2064 B)
constexpr int BSTR = 520;    // u16 per-sample stride in fbuf (1040 B, 16B-aligned)
constexpr size_t WS_FC   = (size_t)2176 * 1024;
constexpr size_t WS_BOTH = WS_FC + (size_t)576 * 1024;

__device__ __forceinline__ unsigned short f2bf(float x) {
    unsigned u = __float_as_uint(x);
    unsigned r = u + 0x7fffu + ((u >> 16) & 1u);
    return (unsigned short)(r >> 16);
}
__device__ __forceinline__ float bf2f(unsigned short h) {
    return __uint_as_float(((unsigned)h) << 16);
}
// hardware v_cvt_pk_bf16_f32 (RNE) — same rounding as f2bf
__device__ __forceinline__ unsigned pkbf(float a, float b) {
    __hip_bfloat162 h = __float22bfloat162_rn(make_float2(a, b));
    return *reinterpret_cast<unsigned*>(&h);
}
__device__ __forceinline__ bf16x8 load8_f32(const float* __restrict__ s) {
    float4 a = *(const float4*)s;
    float4 b = *(const float4*)(s + 4);
    bf16x8 r;
    r[0]=(short)f2bf(a.x); r[1]=(short)f2bf(a.y); r[2]=(short)f2bf(a.z); r[3]=(short)f2bf(a.w);
    r[4]=(short)f2bf(b.x); r[5]=(short)f2bf(b.y); r[6]=(short)f2bf(b.z); r[7]=(short)f2bf(b.w);
    return r;
}

// FC B-frag: lane element j = Wfc[ntile*16+(lane&15)][kg*32+(lane>>4)*8+j]
template<int MODE>
__device__ __forceinline__ bf16x8 fc_bfrag(const unsigned short* __restrict__ wfcb,
                                           const float* __restrict__ Wfc,
                                           int kg, int ntile, int lane)
{
    if constexpr (MODE >= 1) {
        return *(const bf16x8*)(wfcb + (((size_t)(kg * 8 + ntile)) << 9) + lane * 8);
    } else {
        const float* s = Wfc + (size_t)(ntile * 16 + (lane & 15)) * 8704
                             + kg * 32 + (lane >> 4) * 8;
        return load8_f32(s);
    }
}
// hconv B-frag: k = kstep*32+(lane>>4)*8+j -> Wh[H-1][ntile*16+(lane&15)][k>>7][k&127]
template<int MODE>
__device__ __forceinline__ bf16x8 wh_bfrag(const unsigned short* __restrict__ whb,
                                           const float* __restrict__ Wh,
                                           int H, int kstep, int ntile, int lane)
{
    if constexpr (MODE == 2) {
        return *(const bf16x8*)(whb +
            (((size_t)(8 * H * (H - 1) + kstep * 4 + ntile)) << 9) + lane * 8);
    } else {
        const int k = kstep * 32 + (lane >> 4) * 8;
        const float* s = Wh + ((((size_t)(H - 1) * 64 + ntile * 16 + (lane & 15)) * 8
                               + (k >> 7)) * 128 + (k & 127));
        return load8_f32(s);
    }
}

// prep = run the direct loader once per frag, store result (packed == direct)
__global__ __launch_bounds__(256)
void caser_prep(const float* __restrict__ Wfc, const float* __restrict__ Wh,
                unsigned short* __restrict__ wfcb, unsigned short* __restrict__ whb,
                int nfrag)
{
    const int tid = blockIdx.x * 256 + threadIdx.x;
    const int lane = tid & 63, frag = tid >> 6;
    if (frag >= nfrag) return;
    if (frag < 2176) {
        const int kg = frag >> 3, nt = frag & 7;
        bf16x8 v = fc_bfrag<0>(nullptr, Wfc, kg, nt, lane);
        *(bf16x8*)(wfcb + ((size_t)frag << 9) + lane * 8) = v;
    } else {
        const int f2 = frag - 2176;
        int h = 1;
        while (f2 >= 8 * h * (h + 1)) ++h;
        const int fl = f2 - 8 * h * (h - 1);
        const int nt = fl & 3, kstep = fl >> 2;
        bf16x8 v = wh_bfrag<0>(nullptr, Wh, h, kstep, nt, lane);
        *(bf16x8*)(whb + ((size_t)f2 << 9) + lane * 8) = v;
    }
}

// ===================== hconv MFMA (one h, one filter-16-group, one j-parity) =
// D[sample=(lane>>4)*4+r][filter_local=lane&15]  (R6-R10 validated)
template<int H, int PP, int MODE>
__device__ __forceinline__ void hconv_compute(
    const unsigned short* __restrict__ xs,
    const unsigned short* __restrict__ whb, const float* __restrict__ Wh,
    const float* __restrict__ bh,
    int m, int nt4, int lane, int laneA, float mx[4])
{
    constexpr int NJ = 9 - H;
    constexpr int NJS = (PP == 0) ? ((NJ + 1) / 2) : (NJ / 2);
    if constexpr (NJS > 0) {
        f32x4 C[NJS] = {};
        const unsigned short* xbase = xs + m * 16 * XSTR + laneA;
        #pragma unroll
        for (int kstep = 0; kstep < 4 * H; ++kstep) {
            const int hp = kstep >> 2, d0 = (kstep & 3) * 32;
            bf16x8 B = wh_bfrag<MODE>(whb, Wh, H, kstep, nt4, lane);
            #pragma unroll
            for (int idx = 0; idx < NJS; ++idx) {
                const int j = PP + 2 * idx;
                bf16x8 A = *(const bf16x8*)(xbase + (j + hp) * 128 + d0);
                C[idx] = MFMA16(A, B, C[idx]);
            }
        }
        const float bhv = bh[(H - 1) * 64 + nt4 * 16 + (lane & 15)];
        #pragma unroll
        for (int idx = 0; idx < NJS; ++idx)
            #pragma unroll
            for (int r = 0; r < 4; ++r)
                mx[r] = fmaxf(mx[r], fmaxf(C[idx][r] + bhv, 0.f));
    }
}

// one h-step: hconv MFMA -> parity merge -> feat column (H-1)*64 in fbuf0
template<int H, int MODE>
__device__ __forceinline__ void hstep(
    const unsigned short* __restrict__ xs, unsigned short* __restrict__ feat,
    float* __restrict__ cand,
    const unsigned short* __restrict__ whb, const float* __restrict__ Wh,
    const float* __restrict__ bh,
    int t, int lane, int laneA, int hm, int hn4, int pj)
{
    float mx[4] = {};
    if (pj == 0) hconv_compute<H, 0, MODE>(xs, whb, Wh, bh, hm, hn4, lane, laneA, mx);
    else         hconv_compute<H, 1, MODE>(xs, whb, Wh, bh, hm, hn4, lane, laneA, mx);
    #pragma unroll
    for (int r = 0; r < 4; ++r)
        cand[pj * 2176 + (hm * 16 + (lane >> 4) * 4 + r) * 68 +
             hn4 * 16 + (lane & 15)] = mx[r];
    __syncthreads();
    {   // merge 2 parity candidates -> 2 bf16 in feat col (H-1)*64
        const int s = t >> 5, f0 = (t & 31) * 2;
        float a0 = fmaxf(cand[s * 68 + f0],     cand[2176 + s * 68 + f0]);
        float a1 = fmaxf(cand[s * 68 + f0 + 1], cand[2176 + s * 68 + f0 + 1]);
        *(unsigned*)(feat + s * BSTR + (H - 1) * 64 + f0) = pkbf(a0, a1);
    }
    __syncthreads();   // cand reusable by next step
}

// ============================ main fused kernel ==============================
template<int MODE>
__global__ __launch_bounds__(1024, 1)
void caser_main(const int* __restrict__ user_id,
                const int* __restrict__ seq,
                const int* __restrict__ item_id,
                const float* __restrict__ Q,
                const float* __restrict__ Pmat,
                const float* __restrict__ Qp,
                const float* __restrict__ b_item,
                const float* __restrict__ Wv,
                const float* __restrict__ bv,
                const float* __restrict__ Wh,
                const float* __restrict__ bh,
                const float* __restrict__ Wfc,
                const float* __restrict__ bfc,
                const unsigned short* __restrict__ wfcb,
                const unsigned short* __restrict__ whb,
                float* __restrict__ out)
{
    __shared__ unsigned short xs[32 * XSTR];       // 66048 B  x = Q[seq] / zbuf4
    __shared__ unsigned short fbuf[2 * 32 * BSTR]; // 66560 B  ping-pong A-chunks
    __shared__ float cand[2 * 32 * 68];            // 17408 B  hconv cands
    __shared__ float wv_s[576];                    //  2304 B  Wv + bv

    const int t = threadIdx.x;
    const int lane = t & 63;
    const int w = t >> 6;                  // 0..15
    const int b0 = blockIdx.x * 32;
    const int laneA = (lane & 15) * XSTR + (lane >> 4) * 8;
    const int laneB = (lane & 15) * BSTR + (lane >> 4) * 8;
    // FC split: 4 K-quarters x 4 N-groups
    const int kh = w & 3, ng = w >> 2;
    // hconv split: sample-half x filter-16-group x j-parity
    const int hm = w & 1, hn4 = (w >> 1) & 3, pj = (w >> 3) & 1;

    // ---------------- phase 0: weights + x gather ----------------
    if (t < 576) wv_s[t] = (t < 512) ? Wv[t] : bv[t - 512];   // 1024 >= 576: safe
    #pragma unroll
    for (int k = 0; k < 8; ++k) {
        const int idx = t + k * 1024;       // 0..8191 chunks of 4 floats
        const int i = idx & 31;
        const int l = (idx >> 5) & 7;
        const int s = idx >> 8;
        const int it = seq[(b0 + s) * 8 + l];
        float4 v = *(const float4*)(Q + (size_t)it * 128 + i * 4);
        uint2 pk;
        pk.x = pkbf(v.x, v.y);
        pk.y = pkbf(v.z, v.w);
        *(uint2*)(xs + s * XSTR + l * 128 + i * 4) = pk;
    }
    __syncthreads();

    // vconv x slice -> regs: thread (sv=t&31, dq=t>>5) owns d = dq*4..+3
    const int sv = t & 31, dq = t >> 5;
    float xr[8][4];
    #pragma unroll
    for (int l = 0; l < 8; ++l) {
        bf16x4 v = *(const bf16x4*)(xs + sv * XSTR + l * 128 + dq * 4);
        #pragma unroll
        for (int i = 0; i < 4; ++i) xr[l][i] = bf2f((unsigned short)v[i]);
    }

    f32x4 FCC[2][2] = {};

    // ---------------- phase 1: vconv ∥ FC, ping-pong (k = 0..8191) --------
    uint2 vc[4];
    #define VCONV_HALF(hc_, dst_)                                              \
        {                                                                      \
            _Pragma("unroll")                                                  \
            for (int fl = 0; fl < 4; ++fl) {                                   \
                const int f = (hc_) * 4 + fl;                                  \
                const float bvv = wv_s[512 + f];                               \
                float acc[4];                                                  \
                _Pragma("unroll")                                              \
                for (int i = 0; i < 4; ++i) acc[i] = bvv;                      \
                _Pragma("unroll")                                              \
                for (int l = 0; l < 8; ++l) {                                  \
                    const float wl = wv_s[f * 8 + l];                          \
                    _Pragma("unroll")                                          \
                    for (int i = 0; i < 4; ++i)                                \
                        acc[i] = fmaf(xr[l][i], wl, acc[i]);                   \
                }                                                              \
                dst_[fl].x = pkbf(fmaxf(acc[0], 0.f), fmaxf(acc[1], 0.f));     \
                dst_[fl].y = pkbf(fmaxf(acc[2], 0.f), fmaxf(acc[3], 0.f));     \
            }                                                                  \
        }
    #define VSTORE(buf_)                                                       \
        {                                                                      \
            unsigned short* fb = fbuf + (buf_) * (32 * BSTR);                  \
            _Pragma("unroll")                                                  \
            for (int fl = 0; fl < 4; ++fl)                                     \
                *(uint2*)(fb + sv * BSTR + fl * 128 + dq * 4) = vc[fl];        \
        }

    VCONV_HALF(0, vc);
    VSTORE(0);
    __syncthreads();

    #pragma unroll 2
    for (int hc = 0; hc < 16; ++hc) {
        uint2 nxt[4];
        if (hc < 15) VCONV_HALF(hc + 1, nxt);
        {   // FC on buf hc&1 (K=512): wave quarter kh -> kl = kh*4+ks
            const unsigned short* fb = fbuf + (hc & 1) * (32 * BSTR);
            #pragma unroll
            for (int ks = 0; ks < 4; ++ks) {
                const int kl = kh * 4 + ks;
                const int kg = hc * 16 + kl;
                bf16x8 B0 = fc_bfrag<MODE>(wfcb, Wfc, kg, ng * 2,     lane);
                bf16x8 B1 = fc_bfrag<MODE>(wfcb, Wfc, kg, ng * 2 + 1, lane);
                bf16x8 A0 = *(const bf16x8*)(fb + laneB + kl * 32);
                bf16x8 A1 = *(const bf16x8*)(fb + 16 * BSTR + laneB + kl * 32);
                FCC[0][0] = MFMA16(A0, B0, FCC[0][0]);
                FCC[0][1] = MFMA16(A0, B1, FCC[0][1]);
                FCC[1][0] = MFMA16(A1, B0, FCC[1][0]);
                FCC[1][1] = MFMA16(A1, B1, FCC[1][1]);
            }
        }
        if (hc < 15) {
            #pragma unroll
            for (int fl = 0; fl < 4; ++fl) vc[fl] = nxt[fl];
            VSTORE((hc + 1) & 1);
        }
        __syncthreads();
    }
    #undef VCONV_HALF
    #undef VSTORE

    // ---------------- phase 2: MFMA hconv h=1..8 -> feat[32][512] ---------
    unsigned short* feat = fbuf;   // buffer 0, columns 0..511
    hstep<1, MODE>(xs, feat, cand, whb, Wh, bh, t, lane, laneA, hm, hn4, pj);
    hstep<2, MODE>(xs, feat, cand, whb, Wh, bh, t, lane, laneA, hm, hn4, pj);
    hstep<3, MODE>(xs, feat, cand, whb, Wh, bh, t, lane, laneA, hm, hn4, pj);
    hstep<4, MODE>(xs, feat, cand, whb, Wh, bh, t, lane, laneA, hm, hn4, pj);
    hstep<5, MODE>(xs, feat, cand, whb, Wh, bh, t, lane, laneA, hm, hn4, pj);
    hstep<6, MODE>(xs, feat, cand, whb, Wh, bh, t, lane, laneA, hm, hn4, pj);
    hstep<7, MODE>(xs, feat, cand, whb, Wh, bh, t, lane, laneA, hm, hn4, pj);
    hstep<8, MODE>(xs, feat, cand, whb, Wh, bh, t, lane, laneA, hm, hn4, pj);

    // single FC pass over hconv K=512 (kg = 256..271)
    #pragma unroll
    for (int kgi = 0; kgi < 4; ++kgi) {
        const int kloc = kh * 4 + kgi;               // 0..15
        const int kg = 256 + kloc;
        bf16x8 B0 = fc_bfrag<MODE>(wfcb, Wfc, kg, ng * 2,     lane);
        bf16x8 B1 = fc_bfrag<MODE>(wfcb, Wfc, kg, ng * 2 + 1, lane);
        bf16x8 A0 = *(const bf16x8*)(feat + laneB + kloc * 32);
        bf16x8 A1 = *(const bf16x8*)(feat + 16 * BSTR + laneB + kloc * 32);
        FCC[0][0] = MFMA16(A0, B0, FCC[0][0]);
        FCC[0][1] = MFMA16(A0, B1, FCC[0][1]);
        FCC[1][0] = MFMA16(A1, B0, FCC[1][0]);
        FCC[1][1] = MFMA16(A1, B1, FCC[1][1]);
    }

    // ---------------- epilogue: 4-quarter merge, relu, score --------------
    float* zbuf4 = (float*)xs;   // [4][32][132] overlay on dead xs (67584 B)
    #pragma unroll
    for (int m = 0; m < 2; ++m)
        #pragma unroll
        for (int nt = 0; nt < 2; ++nt)
            #pragma unroll
            for (int r = 0; r < 4; ++r)
                zbuf4[kh * (32 * 132) + (m * 16 + (lane >> 4) * 4 + r) * 132 +
                      ng * 32 + nt * 16 + (lane & 15)] = FCC[m][nt][r];
    __syncthreads();
    {
        const int s = t >> 5, l32 = t & 31, o0 = l32 * 4;
        const int b = b0 + s;
        const int item = item_id[b];
        const int user = user_id[b];
        const float* qp = Qp + (size_t)item * 256;
        const float* pu = Pmat + (size_t)user * 128;
        float acc2 = 0.f;
        #pragma unroll
        for (int i = 0; i < 4; ++i) {
            float z = zbuf4[s * 132 + o0 + i]
                    + zbuf4[1 * (32 * 132) + s * 132 + o0 + i]
                    + zbuf4[2 * (32 * 132) + s * 132 + o0 + i]
                    + zbuf4[3 * (32 * 132) + s * 132 + o0 + i]
                    + bfc[o0 + i];
            z = fmaxf(z, 0.f);
            acc2 = fmaf(z, qp[o0 + i], acc2);
        }
        #pragma unroll
        for (int i = 0; i < 4; ++i)
            acc2 = fmaf(pu[o0 + i], qp[128 + o0 + i], acc2);
        acc2 += __shfl_xor(acc2, 1, 32);
        acc2 += __shfl_xor(acc2, 2, 32);
        acc2 += __shfl_xor(acc2, 4, 32);
        acc2 += __shfl_xor(acc2, 8, 32);
        acc2 += __shfl_xor(acc2, 16, 32);
        if (l32 == 0) out[b] = acc2 + b_item[item];
    }
}

extern "C" void kernel_launch(void* const* d_in, const int* in_sizes, int n_in,
                              void* d_out, int out_size, void* d_ws, size_t ws_size,
                              hipStream_t stream)
{
    const int*   user_id = (const int*)  d_in[0];
    const int*   seq     = (const int*)  d_in[1];
    const int*   item_id = (const int*)  d_in[2];
    const float* Q       = (const float*)d_in[3];
    const float* Pmat    = (const float*)d_in[4];
    const float* Qp      = (const float*)d_in[5];
    const float* b_item  = (const float*)d_in[6];
    const float* Wv      = (const float*)d_in[7];
    const float* bv      = (const float*)d_in[8];
    const float* Wh      = (const float*)d_in[9];
    const float* bh      = (const float*)d_in[10];
    const float* Wfc     = (const float*)d_in[11];
    const float* bfc     = (const float*)d_in[12];
    float* out = (float*)d_out;

    unsigned short* wfcb = (unsigned short*)d_ws;
    unsigned short* whb  = wfcb + WS_FC / 2;

    if (ws_size >= WS_BOTH) {
        hipLaunchKernelGGL(caser_prep, dim3(688), dim3(256), 0, stream,
                           Wfc, Wh, wfcb, whb, 2752);
        hipLaunchKernelGGL((caser_main<2>), dim3(256), dim3(1024), 0, stream,
                           user_id, seq, item_id, Q, Pmat, Qp, b_item,
                           Wv, bv, Wh, bh, Wfc, bfc, wfcb, whb, out);
    } else if (ws_size >= WS_FC) {
        hipLaunchKernelGGL(caser_prep, dim3(544), dim3(256), 0, stream,
                           Wfc, Wh, wfcb, whb, 2176);
        hipLaunchKernelGGL((caser_main<1>), dim3(256), dim3(1024), 0, stream,
                           user_id, seq, item_id, Q, Pmat, Qp, b_item,
                           Wv, bv, Wh, bh, Wfc, bfc, wfcb, whb, out);
    } else {
        hipLaunchKernelGGL((caser_main<0>), dim3(256), dim3(1024), 0, stream,
                           user_id, seq, item_id, Q, Pmat, Qp, b_item,
                           Wv, bv, Wh, bh, Wfc, bfc,
                           (const unsigned short*)nullptr, (const unsigned short*)nullptr, out);
    }
}

// Round 12
// 78.436 us; speedup vs baseline: 61.7945x; 1.0948x over previous
//
#include <hip/hip_runtime.h>
#include <hip/hip_bf16.h>
#include <cstdint>
#include <cstddef>

typedef short bf16x8 __attribute__((ext_vector_type(8)));
typedef short bf16x4 __attribute__((ext_vector_type(4)));
typedef float f32x4  __attribute__((ext_vector_type(4)));

#define MFMA16(A, B, C) __builtin_amdgcn_mfma_f32_16x16x32_bf16(A, B, C, 0, 0, 0)

constexpr int XSTR = 1032;   // u16 row stride per sample strip in xs (2064 B)
constexpr int BSTR = 520;    // u16 per-sample stride in fbuf (1040 B, 16B-aligned)
constexpr size_t WS_FC   = (size_t)2176 * 1024;
constexpr size_t WS_BOTH = WS_FC + (size_t)576 * 1024;

__device__ __forceinline__ unsigned short f2bf(float x) {
    unsigned u = __float_as_uint(x);
    unsigned r = u + 0x7fffu + ((u >> 16) & 1u);
    return (unsigned short)(r >> 16);
}
__device__ __forceinline__ float bf2f(unsigned short h) {
    return __uint_as_float(((unsigned)h) << 16);
}
// hardware v_cvt_pk_bf16_f32 (RNE) — same rounding as f2bf
__device__ __forceinline__ unsigned pkbf(float a, float b) {
    __hip_bfloat162 h = __float22bfloat162_rn(make_float2(a, b));
    return *reinterpret_cast<unsigned*>(&h);
}
__device__ __forceinline__ bf16x8 load8_f32(const float* __restrict__ s) {
    float4 a = *(const float4*)s;
    float4 b = *(const float4*)(s + 4);
    bf16x8 r;
    r[0]=(short)f2bf(a.x); r[1]=(short)f2bf(a.y); r[2]=(short)f2bf(a.z); r[3]=(short)f2bf(a.w);
    r[4]=(short)f2bf(b.x); r[5]=(short)f2bf(b.y); r[6]=(short)f2bf(b.z); r[7]=(short)f2bf(b.w);
    return r;
}

// FC B-frag: lane element j = Wfc[ntile*16+(lane&15)][kg*32+(lane>>4)*8+j]
template<int MODE>
__device__ __forceinline__ bf16x8 fc_bfrag(const unsigned short* __restrict__ wfcb,
                                           const float* __restrict__ Wfc,
                                           int kg, int ntile, int lane)
{
    if constexpr (MODE >= 1) {
        return *(const bf16x8*)(wfcb + (((size_t)(kg * 8 + ntile)) << 9) + lane * 8);
    } else {
        const float* s = Wfc + (size_t)(ntile * 16 + (lane & 15)) * 8704
                             + kg * 32 + (lane >> 4) * 8;
        return load8_f32(s);
    }
}
// hconv B-frag: k = kstep*32+(lane>>4)*8+j -> Wh[H-1][ntile*16+(lane&15)][k>>7][k&127]
template<int MODE>
__device__ __forceinline__ bf16x8 wh_bfrag(const unsigned short* __restrict__ whb,
                                           const float* __restrict__ Wh,
                                           int H, int kstep, int ntile, int lane)
{
    if constexpr (MODE == 2) {
        return *(const bf16x8*)(whb +
            (((size_t)(8 * H * (H - 1) + kstep * 4 + ntile)) << 9) + lane * 8);
    } else {
        const int k = kstep * 32 + (lane >> 4) * 8;
        const float* s = Wh + ((((size_t)(H - 1) * 64 + ntile * 16 + (lane & 15)) * 8
                               + (k >> 7)) * 128 + (k & 127));
        return load8_f32(s);
    }
}

// prep = run the direct loader once per frag, store result (packed == direct)
__global__ __launch_bounds__(256)
void caser_prep(const float* __restrict__ Wfc, const float* __restrict__ Wh,
                unsigned short* __restrict__ wfcb, unsigned short* __restrict__ whb,
                int nfrag)
{
    const int tid = blockIdx.x * 256 + threadIdx.x;
    const int lane = tid & 63, frag = tid >> 6;
    if (frag >= nfrag) return;
    if (frag < 2176) {
        const int kg = frag >> 3, nt = frag & 7;
        bf16x8 v = fc_bfrag<0>(nullptr, Wfc, kg, nt, lane);
        *(bf16x8*)(wfcb + ((size_t)frag << 9) + lane * 8) = v;
    } else {
        const int f2 = frag - 2176;
        int h = 1;
        while (f2 >= 8 * h * (h + 1)) ++h;
        const int fl = f2 - 8 * h * (h - 1);
        const int nt = fl & 3, kstep = fl >> 2;
        bf16x8 v = wh_bfrag<0>(nullptr, Wh, h, kstep, nt, lane);
        *(bf16x8*)(whb + ((size_t)f2 << 9) + lane * 8) = v;
    }
}

// ===================== hconv MFMA (one h, one filter-16-group, one j-parity) =
// D[sample=(lane>>4)*4+r][filter_local=lane&15]  (R6-R11 validated)
template<int H, int PP, int MODE>
__device__ __forceinline__ void hconv_compute(
    const unsigned short* __restrict__ xs,
    const unsigned short* __restrict__ whb, const float* __restrict__ Wh,
    const float* __restrict__ bh,
    int m, int nt4, int lane, int laneA, float mx[4])
{
    constexpr int NJ = 9 - H;
    constexpr int NJS = (PP == 0) ? ((NJ + 1) / 2) : (NJ / 2);
    if constexpr (NJS > 0) {
        f32x4 C[NJS] = {};
        const unsigned short* xbase = xs + m * 16 * XSTR + laneA;
        #pragma unroll
        for (int kstep = 0; kstep < 4 * H; ++kstep) {
            const int hp = kstep >> 2, d0 = (kstep & 3) * 32;
            bf16x8 B = wh_bfrag<MODE>(whb, Wh, H, kstep, nt4, lane);
            #pragma unroll
            for (int idx = 0; idx < NJS; ++idx) {
                const int j = PP + 2 * idx;
                bf16x8 A = *(const bf16x8*)(xbase + (j + hp) * 128 + d0);
                C[idx] = MFMA16(A, B, C[idx]);
            }
        }
        const float bhv = bh[(H - 1) * 64 + nt4 * 16 + (lane & 15)];
        #pragma unroll
        for (int idx = 0; idx < NJS; ++idx)
            #pragma unroll
            for (int r = 0; r < 4; ++r)
                mx[r] = fmaxf(mx[r], fmaxf(C[idx][r] + bhv, 0.f));
    }
}

// one h-step: hconv MFMA -> parity merge (alternating cand buffer) ->
// feat column (H-1)*64. ONE barrier per step (cand_h reused only at h+2,
// and merge_h precedes BAR_{h+1} in program order -> safe).
template<int H, int MODE>
__device__ __forceinline__ void hstep(
    const unsigned short* __restrict__ xs, unsigned short* __restrict__ feat,
    float* __restrict__ candc,
    const unsigned short* __restrict__ whb, const float* __restrict__ Wh,
    const float* __restrict__ bh,
    int t, int lane, int laneA, int hm, int hn4, int pj)
{
    float mx[4] = {};
    if (pj == 0) hconv_compute<H, 0, MODE>(xs, whb, Wh, bh, hm, hn4, lane, laneA, mx);
    else         hconv_compute<H, 1, MODE>(xs, whb, Wh, bh, hm, hn4, lane, laneA, mx);
    #pragma unroll
    for (int r = 0; r < 4; ++r)
        candc[pj * 2176 + (hm * 16 + (lane >> 4) * 4 + r) * 68 +
              hn4 * 16 + (lane & 15)] = mx[r];
    __syncthreads();
    {   // merge 2 parity candidates -> 2 bf16 in feat col (H-1)*64
        const int s = t >> 5, f0 = (t & 31) * 2;
        float a0 = fmaxf(candc[s * 68 + f0],     candc[2176 + s * 68 + f0]);
        float a1 = fmaxf(candc[s * 68 + f0 + 1], candc[2176 + s * 68 + f0 + 1]);
        *(unsigned*)(feat + s * BSTR + (H - 1) * 64 + f0) = pkbf(a0, a1);
    }
    // no trailing barrier
}

// ============================ main fused kernel ==============================
template<int MODE>
__global__ __launch_bounds__(1024, 1)
void caser_main(const int* __restrict__ user_id,
                const int* __restrict__ seq,
                const int* __restrict__ item_id,
                const float* __restrict__ Q,
                const float* __restrict__ Pmat,
                const float* __restrict__ Qp,
                const float* __restrict__ b_item,
                const float* __restrict__ Wv,
                const float* __restrict__ bv,
                const float* __restrict__ Wh,
                const float* __restrict__ bh,
                const float* __restrict__ Wfc,
                const float* __restrict__ bfc,
                const unsigned short* __restrict__ wfcb,
                const unsigned short* __restrict__ whb,
                float* __restrict__ out)
{
    __shared__ unsigned short xs[32 * XSTR];       // 66048 B  x = Q[seq] / zbuf4
    __shared__ unsigned short fbuf[2 * 32 * BSTR]; // 66560 B  ping-pong / candB
    __shared__ float cand[2 * 32 * 68];            // 17408 B  hconv candA
    __shared__ float wv_s[576];                    //  2304 B  Wv + bv

    const int t = threadIdx.x;
    const int lane = t & 63;
    const int w = t >> 6;                  // 0..15
    const int b0 = blockIdx.x * 32;
    const int laneA = (lane & 15) * XSTR + (lane >> 4) * 8;
    const int laneB = (lane & 15) * BSTR + (lane >> 4) * 8;
    // FC split: 4 K-quarters x 4 N-groups
    const int kh = w & 3, ng = w >> 2;
    // hconv split: sample-half x filter-16-group x j-parity
    const int hm = w & 1, hn4 = (w >> 1) & 3, pj = (w >> 3) & 1;

    // ---------------- phase 0: weights + x gather ----------------
    if (t < 576) wv_s[t] = (t < 512) ? Wv[t] : bv[t - 512];   // 1024 >= 576: safe
    #pragma unroll
    for (int k = 0; k < 8; ++k) {
        const int idx = t + k * 1024;       // 0..8191 chunks of 4 floats
        const int i = idx & 31;
        const int l = (idx >> 5) & 7;
        const int s = idx >> 8;
        const int it = seq[(b0 + s) * 8 + l];
        float4 v = *(const float4*)(Q + (size_t)it * 128 + i * 4);
        uint2 pk;
        pk.x = pkbf(v.x, v.y);
        pk.y = pkbf(v.z, v.w);
        *(uint2*)(xs + s * XSTR + l * 128 + i * 4) = pk;
    }
    __syncthreads();

    // vconv x slice -> regs: thread (sv=t&31, dq=t>>5) owns d = dq*4..+3
    const int sv = t & 31, dq = t >> 5;
    float xr[8][4];
    #pragma unroll
    for (int l = 0; l < 8; ++l) {
        bf16x4 v = *(const bf16x4*)(xs + sv * XSTR + l * 128 + dq * 4);
        #pragma unroll
        for (int i = 0; i < 4; ++i) xr[l][i] = bf2f((unsigned short)v[i]);
    }

    f32x4 FCC[2][2] = {};

    // ---------------- phase 1: vconv ∥ FC, ping-pong + B-prefetch ---------
    uint2 vc[4];
    #define VCONV_HALF(hc_)                                                    \
        {                                                                      \
            _Pragma("unroll")                                                  \
            for (int fl = 0; fl < 4; ++fl) {                                   \
                const int f = (hc_) * 4 + fl;                                  \
                const float bvv = wv_s[512 + f];                               \
                float acc[4];                                                  \
                _Pragma("unroll")                                              \
                for (int i = 0; i < 4; ++i) acc[i] = bvv;                      \
                _Pragma("unroll")                                              \
                for (int l = 0; l < 8; ++l) {                                  \
                    const float wl = wv_s[f * 8 + l];                          \
                    _Pragma("unroll")                                          \
                    for (int i = 0; i < 4; ++i)                                \
                        acc[i] = fmaf(xr[l][i], wl, acc[i]);                   \
                }                                                              \
                vc[fl].x = pkbf(fmaxf(acc[0], 0.f), fmaxf(acc[1], 0.f));       \
                vc[fl].y = pkbf(fmaxf(acc[2], 0.f), fmaxf(acc[3], 0.f));       \
            }                                                                  \
        }
    #define VSTORE(buf_)                                                       \
        {                                                                      \
            unsigned short* fb = fbuf + (buf_) * (32 * BSTR);                  \
            _Pragma("unroll")                                                  \
            for (int fl = 0; fl < 4; ++fl)                                     \
                *(uint2*)(fb + sv * BSTR + fl * 128 + dq * 4) = vc[fl];        \
        }

    bf16x8 BF0[4], BF1[4];
    #pragma unroll
    for (int ks = 0; ks < 4; ++ks) {
        const int kg = kh * 4 + ks;
        BF0[ks] = fc_bfrag<MODE>(wfcb, Wfc, kg, ng * 2,     lane);
        BF1[ks] = fc_bfrag<MODE>(wfcb, Wfc, kg, ng * 2 + 1, lane);
    }
    VCONV_HALF(0);
    VSTORE(0);
    __syncthreads();

    #pragma unroll 1
    for (int hc = 0; hc < 16; ++hc) {
        {   // FC on buf hc&1 using prefetched B-frags
            const unsigned short* fb = fbuf + (hc & 1) * (32 * BSTR);
            #pragma unroll
            for (int ks = 0; ks < 4; ++ks) {
                const int kl = kh * 4 + ks;
                bf16x8 A0 = *(const bf16x8*)(fb + laneB + kl * 32);
                bf16x8 A1 = *(const bf16x8*)(fb + 16 * BSTR + laneB + kl * 32);
                FCC[0][0] = MFMA16(A0, BF0[ks], FCC[0][0]);
                FCC[0][1] = MFMA16(A0, BF1[ks], FCC[0][1]);
                FCC[1][0] = MFMA16(A1, BF0[ks], FCC[1][0]);
                FCC[1][1] = MFMA16(A1, BF1[ks], FCC[1][1]);
            }
        }
        if (hc < 15) {
            // prefetch next iteration's B-frags; latency hides under
            // vconv VALU + VSTORE + barrier
            #pragma unroll
            for (int ks = 0; ks < 4; ++ks) {
                const int kg = (hc + 1) * 16 + kh * 4 + ks;
                BF0[ks] = fc_bfrag<MODE>(wfcb, Wfc, kg, ng * 2,     lane);
                BF1[ks] = fc_bfrag<MODE>(wfcb, Wfc, kg, ng * 2 + 1, lane);
            }
            VCONV_HALF(hc + 1);
            VSTORE((hc + 1) & 1);
        }
        __syncthreads();
    }
    #undef VCONV_HALF
    #undef VSTORE

    // ---------------- phase 2: MFMA hconv h=1..8 -> feat[32][512] ---------
    unsigned short* feat = fbuf;                      // buffer 0, cols 0..511
    float* candA = cand;
    float* candB = (float*)(fbuf + 32 * BSTR);        // dead buffer 1 (33 KB)
    hstep<1, MODE>(xs, feat, candA, whb, Wh, bh, t, lane, laneA, hm, hn4, pj);
    hstep<2, MODE>(xs, feat, candB, whb, Wh, bh, t, lane, laneA, hm, hn4, pj);
    hstep<3, MODE>(xs, feat, candA, whb, Wh, bh, t, lane, laneA, hm, hn4, pj);
    hstep<4, MODE>(xs, feat, candB, whb, Wh, bh, t, lane, laneA, hm, hn4, pj);
    hstep<5, MODE>(xs, feat, candA, whb, Wh, bh, t, lane, laneA, hm, hn4, pj);
    hstep<6, MODE>(xs, feat, candB, whb, Wh, bh, t, lane, laneA, hm, hn4, pj);
    hstep<7, MODE>(xs, feat, candA, whb, Wh, bh, t, lane, laneA, hm, hn4, pj);
    hstep<8, MODE>(xs, feat, candB, whb, Wh, bh, t, lane, laneA, hm, hn4, pj);

    // prefetch final-FC B-frags; latency hides under the feat barrier
    #pragma unroll
    for (int kgi = 0; kgi < 4; ++kgi) {
        const int kg = 256 + kh * 4 + kgi;
        BF0[kgi] = fc_bfrag<MODE>(wfcb, Wfc, kg, ng * 2,     lane);
        BF1[kgi] = fc_bfrag<MODE>(wfcb, Wfc, kg, ng * 2 + 1, lane);
    }
    __syncthreads();   // all feat columns written

    // single FC pass over hconv K=512 (kg = 256..271)
    #pragma unroll
    for (int kgi = 0; kgi < 4; ++kgi) {
        const int kloc = kh * 4 + kgi;               // 0..15
        bf16x8 A0 = *(const bf16x8*)(feat + laneB + kloc * 32);
        bf16x8 A1 = *(const bf16x8*)(feat + 16 * BSTR + laneB + kloc * 32);
        FCC[0][0] = MFMA16(A0, BF0[kgi], FCC[0][0]);
        FCC[0][1] = MFMA16(A0, BF1[kgi], FCC[0][1]);
        FCC[1][0] = MFMA16(A1, BF0[kgi], FCC[1][0]);
        FCC[1][1] = MFMA16(A1, BF1[kgi], FCC[1][1]);
    }

    // ---------------- epilogue: 4-quarter merge, relu, score --------------
    float* zbuf4 = (float*)xs;   // [4][32][132] overlay on dead xs (67584 B)
    #pragma unroll
    for (int m = 0; m < 2; ++m)
        #pragma unroll
        for (int nt = 0; nt < 2; ++nt)
            #pragma unroll
            for (int r = 0; r < 4; ++r)
                zbuf4[kh * (32 * 132) + (m * 16 + (lane >> 4) * 4 + r) * 132 +
                      ng * 32 + nt * 16 + (lane & 15)] = FCC[m][nt][r];
    __syncthreads();
    {
        const int s = t >> 5, l32 = t & 31, o0 = l32 * 4;
        const int b = b0 + s;
        const int item = item_id[b];
        const int user = user_id[b];
        const float* qp = Qp + (size_t)item * 256;
        const float* pu = Pmat + (size_t)user * 128;
        float acc2 = 0.f;
        #pragma unroll
        for (int i = 0; i < 4; ++i) {
            float z = zbuf4[s * 132 + o0 + i]
                    + zbuf4[1 * (32 * 132) + s * 132 + o0 + i]
                    + zbuf4[2 * (32 * 132) + s * 132 + o0 + i]
                    + zbuf4[3 * (32 * 132) + s * 132 + o0 + i]
                    + bfc[o0 + i];
            z = fmaxf(z, 0.f);
            acc2 = fmaf(z, qp[o0 + i], acc2);
        }
        #pragma unroll
        for (int i = 0; i < 4; ++i)
            acc2 = fmaf(pu[o0 + i], qp[128 + o0 + i], acc2);
        acc2 += __shfl_xor(acc2, 1, 32);
        acc2 += __shfl_xor(acc2, 2, 32);
        acc2 += __shfl_xor(acc2, 4, 32);
        acc2 += __shfl_xor(acc2, 8, 32);
        acc2 += __shfl_xor(acc2, 16, 32);
        if (l32 == 0) out[b] = acc2 + b_item[item];
    }
}

extern "C" void kernel_launch(void* const* d_in, const int* in_sizes, int n_in,
                              void* d_out, int out_size, void* d_ws, size_t ws_size,
                              hipStream_t stream)
{
    const int*   user_id = (const int*)  d_in[0];
    const int*   seq     = (const int*)  d_in[1];
    const int*   item_id = (const int*)  d_in[2];
    const float* Q       = (const float*)d_in[3];
    const float* Pmat    = (const float*)d_in[4];
    const float* Qp      = (const float*)d_in[5];
    const float* b_item  = (const float*)d_in[6];
    const float* Wv      = (const float*)d_in[7];
    const float* bv      = (const float*)d_in[8];
    const float* Wh      = (const float*)d_in[9];
    const float* bh      = (const float*)d_in[10];
    const float* Wfc     = (const float*)d_in[11];
    const float* bfc     = (const float*)d_in[12];
    float* out = (float*)d_out;

    unsigned short* wfcb = (unsigned short*)d_ws;
    unsigned short* whb  = wfcb + WS_FC / 2;

    if (ws_size >= WS_BOTH) {
        hipLaunchKernelGGL(caser_prep, dim3(688), dim3(256), 0, stream,
                           Wfc, Wh, wfcb, whb, 2752);
        hipLaunchKernelGGL((caser_main<2>), dim3(256), dim3(1024), 0, stream,
                           user_id, seq, item_id, Q, Pmat, Qp, b_item,
                           Wv, bv, Wh, bh, Wfc, bfc, wfcb, whb, out);
    } else if (ws_size >= WS_FC) {
        hipLaunchKernelGGL(caser_prep, dim3(544), dim3(256), 0, stream,
                           Wfc, Wh, wfcb, whb, 2176);
        hipLaunchKernelGGL((caser_main<1>), dim3(256), dim3(1024), 0, stream,
                           user_id, seq, item_id, Q, Pmat, Qp, b_item,
                           Wv, bv, Wh, bh, Wfc, bfc, wfcb, whb, out);
    } else {
        hipLaunchKernelGGL((caser_main<0>), dim3(256), dim3(1024), 0, stream,
                           user_id, seq, item_id, Q, Pmat, Qp, b_item,
                           Wv, bv, Wh, bh, Wfc, bfc,
                           (const unsigned short*)nullptr, (const unsigned short*)nullptr, out);
    }
}